// Round 19
// baseline (1017.179 us; speedup 1.0000x reference)
//
#include <hip/hip_runtime.h>
#include <hip/hip_bf16.h>
#include <hip/hip_fp8.h>
#include <cmath>

typedef __hip_bfloat16 bf16;
typedef __attribute__((ext_vector_type(8))) short s16x8;
typedef __attribute__((ext_vector_type(4))) float f32x4v;

__device__ __forceinline__ float bf2f(bf16 v){ return __bfloat162float(v); }
__device__ __forceinline__ bf16  f2bf(float v){ return __float2bfloat16(v); }
__device__ __forceinline__ unsigned char f2fp8(float v){
  __hip_fp8_e4m3 q(v);
  return *reinterpret_cast<unsigned char*>(&q);
}

__device__ __forceinline__ void gload16(const void* g, void* l){
  __builtin_amdgcn_global_load_lds((const __attribute__((address_space(1))) void*)g,
                                   (__attribute__((address_space(3))) void*)l,
                                   16, 0, 0);
}

// bijective XCD-chunk swizzle (m204)
__device__ __forceinline__ int xcd_swizzle(int bid, int nb){
  int q = nb >> 3, r = nb & 7;
  int xcd = bid & 7, idx = bid >> 3;
  return (xcd < r) ? (xcd*(q+1) + idx) : (r + xcd*q + idx);
}

// tanh-form GELU
__device__ __forceinline__ float gelu_f(float v){
  float y = 0.797884561f*(v + 0.044715f*v*v*v);
  float e = __expf(-2.f*y);
  return v * __builtin_amdgcn_rcpf(1.f + e);
}

// ---------------- merged weight fp32 -> bf16 (qkv | proj) ----------------
__global__ void k_f2bf2(const float* __restrict__ s0, const float* __restrict__ s1,
                        bf16* __restrict__ out){
  int i = blockIdx.x*256 + threadIdx.x;
  if (i >= 589824) return;
  out[i] = f2bf(i < 442368 ? s0[i] : s1[i - 442368]);
}
// fc1 | fc2 fp32 -> fp8 (589824 each)
__global__ void k_f2fp8w(const float* __restrict__ s0, const float* __restrict__ s1,
                         unsigned char* __restrict__ o0, unsigned char* __restrict__ o1){
  int i = blockIdx.x*256 + threadIdx.x;
  if (i >= 589824) return;
  o0[i] = f2fp8(s0[i]);
  o1[i] = f2fp8(s1[i]);
}

// ------- combined bias+mask table (f32), MFMA-C-layout:
// comb[clshead][row>>2][col][row&3]  -> per-lane f32x4 = 4 accumulator rows
__global__ void k_comb(const float* __restrict__ rpb, float* __restrict__ comb){
  int idx = blockIdx.x*256 + threadIdx.x;        // 96*128*128
  int col = idx & 127, row = (idx>>7)&127, clshead = idx>>14;
  int cls = clshead/12, head = clshead - cls*12;
  float v;
  if (row >= 98) v = 0.f;
  else if (col >= 98) v = -10000.f;
  else {
    int qd = row/49, qr = row%49, qh = qr/7, qw = qr%7;
    int kd = col/49, kr = col%49, kh = kr/7, kw = kr%7;
    int pbq = qd*169 + qh*13 + qw;
    int pbk = kd*169 + kh*13 + kw;
    int lq, lk;
    {
      int ld = (cls&4) ? (qd==0?1:2) : 0;
      int lh = (cls&2) ? (qh<4?1:2) : 0;
      int lw = (cls&1) ? (qw<4?1:2) : 0;
      lq = ld*9+lh*3+lw;
    }
    {
      int ld = (cls&4) ? (kd==0?1:2) : 0;
      int lh = (cls&2) ? (kh<4?1:2) : 0;
      int lw = (cls&1) ? (kw<4?1:2) : 0;
      lk = ld*9+lh*3+lw;
    }
    float bias = rpb[(pbq-pbk+253)*12 + head];
    v = bias + ((lq!=lk) ? -100.f : 0.f);
  }
  comb[(((size_t)clshead*32 + (row>>2))*128 + col)*4 + (row&3)] = v;
}

// ------- LN1 + cyclic shift + window partition (one wave per token) -------
__global__ __launch_bounds__(256)
void k_ln1(const float* __restrict__ x, const float* __restrict__ g,
           const float* __restrict__ b, bf16* __restrict__ xw, long tbase)
{
  int tl = blockIdx.x*4 + (threadIdx.x>>6);
  long t = tbase + tl;
  int lane = threadIdx.x & 63;
  int win = (int)(t / 98), n = (int)(t % 98);
  int batch = win>>8;
  int wq = win & 7, hq = (win>>3)&7, dq = (win>>6)&3;
  int dr = n/49, rem = n%49, hr = rem/7, wr = rem%7;
  int d = dq*2+dr, h = hq*7+hr, w = wq*7+wr;
  int sd = (d+1)&7;
  int sh = h+3; if (sh>=56) sh-=56;
  int sw = w+3; if (sw>=56) sw-=56;
  const float* row = x + ((size_t)(((batch*8+sd)*56+sh)*56+sw))*384;
  float v[6]; float s=0.f, ss=0.f;
  int c0 = lane*6;
  #pragma unroll
  for (int i=0;i<6;++i){ float f = row[c0+i]; v[i]=f; s+=f; ss+=f*f; }
  #pragma unroll
  for (int o=32;o>0;o>>=1){ s += __shfl_xor(s,o); ss += __shfl_xor(ss,o); }
  float mu = s*(1.f/384.f);
  float var = ss*(1.f/384.f) - mu*mu;
  float rstd = rsqrtf(var + 1e-5f);
  bf16* orow = xw + (size_t)tl*384;
  #pragma unroll
  for (int i=0;i<6;++i){ int c=c0+i; orow[c] = f2bf((v[i]-mu)*rstd*g[c] + b[c]); }
}

// ------- bf16 MFMA GEMM: tile 128x192, wave tile 64x96, BK=64 (R16 best) -------
// EPI: 0 bias->bf16; 3 bias, scale cols<384 ->bf16
template<int EPI, int KT>   // KT = K/64
__global__ __launch_bounds__(256, 2)
void k_gemm192(const bf16* __restrict__ A, const bf16* __restrict__ B,
               const float* __restrict__ bias, const float* __restrict__ resid,
               void* __restrict__ outp, int N, int nx)
{
  constexpr int K = KT*64;
  __shared__ __align__(16) bf16 As[2][128*64];   // 32 KB
  __shared__ __align__(16) bf16 Bs[2][192*64];   // 48 KB
  const int tid = threadIdx.x;
  const int wave = tid>>6, lane = tid&63;
  const int wg = xcd_swizzle(blockIdx.x, gridDim.x);
  const int tn = wg % nx, tm = wg / nx;
  const int wm = wave>>1, wn = wave&1;
  const int fr = lane & 15, l4 = lane>>4;

  f32x4v acc[4][6];
  #pragma unroll
  for (int i=0;i<4;++i)
    #pragma unroll
    for (int j=0;j<6;++j)
      #pragma unroll
      for (int e=0;e<4;++e) acc[i][j][e] = 0.f;

  const int lr8 = lane>>3, lc8 = lane&7;
  const size_t lane_src = (size_t)lr8*K + (size_t)((lc8 ^ lr8)*8);
  const bf16* gA = A + ((size_t)tm*128 + wave*32)*K + lane_src;
  const bf16* gB = B + ((size_t)tn*192 + wave*48)*K + lane_src;

  auto stage = [&](int buf, int koff){
    #pragma unroll
    for (int j=0;j<4;++j)
      gload16(gA + (size_t)(j*8)*K + koff, &As[buf][(wave*32 + j*8)*64]);
    #pragma unroll
    for (int j=0;j<6;++j)
      gload16(gB + (size_t)(j*8)*K + koff, &Bs[buf][(wave*48 + j*8)*64]);
  };

  stage(0, 0);
  const int slot0 = (l4 ^ (fr & 7)) * 8;

  #pragma unroll 2
  for (int kt=0; kt<KT; ++kt){
    asm volatile("s_waitcnt vmcnt(0) lgkmcnt(0)" ::: "memory");
    __builtin_amdgcn_s_barrier();
    if (kt+1 < KT) stage((kt+1)&1, (kt+1)*64);
    const bf16* Ab = As[kt&1];
    const bf16* Bb = Bs[kt&1];
    s16x8 af[4][2], bfr[6][2];
    #pragma unroll
    for (int i=0;i<4;++i){
      int ra = (wm*64 + i*16 + fr)*64;
      af[i][0] = *(const s16x8*)&Ab[ra + slot0];
      af[i][1] = *(const s16x8*)&Ab[ra + (slot0^32)];
    }
    #pragma unroll
    for (int i=0;i<6;++i){
      int rb = (wn*96 + i*16 + fr)*64;
      bfr[i][0] = *(const s16x8*)&Bb[rb + slot0];
      bfr[i][1] = *(const s16x8*)&Bb[rb + (slot0^32)];
    }
    #pragma unroll
    for (int mi=0;mi<4;++mi)
      #pragma unroll
      for (int ni=0;ni<6;++ni)
        #pragma unroll
        for (int kk=0;kk<2;++kk)
          acc[mi][ni] = __builtin_amdgcn_mfma_f32_16x16x32_bf16(af[mi][kk], bfr[ni][kk], acc[mi][ni], 0,0,0);
  }

  #pragma unroll
  for (int mi=0;mi<4;++mi){
    #pragma unroll
    for (int ni=0;ni<6;++ni){
      int col = tn*192 + wn*96 + ni*16 + fr;
      float bv = bias[col];
      int rowb = tm*128 + wm*64 + mi*16 + l4*4;
      #pragma unroll
      for (int r=0;r<4;++r){
        size_t idx = (size_t)(rowb+r)*N + col;
        float v = acc[mi][ni][r] + bv;
        if (EPI==0){
          ((bf16*)outp)[idx] = f2bf(v);
        } else {
          if (col < 384) v *= 0.17677669529663687f;
          ((bf16*)outp)[idx] = f2bf(v);
        }
      }
    }
  }
}

// ------- fp8 MFMA GEMM: tile 128x192, wave tile 64x96, BK=128 bytes (R17) -------
// EPI: 1 bias+GELU -> fp8; 2 bias+resid -> f32
template<int EPI, int KTB>   // KTB = K/128
__global__ __launch_bounds__(256, 2)
void k_gemm_fp8(const unsigned char* __restrict__ A, const unsigned char* __restrict__ B,
                const float* __restrict__ bias, const float* __restrict__ resid,
                void* __restrict__ outp, int N, int nx)
{
  constexpr int K = KTB*128;                       // bytes per row
  __shared__ __align__(16) unsigned char As[2][128*128];   // 32 KB
  __shared__ __align__(16) unsigned char Bs[2][192*128];   // 48 KB
  const int tid = threadIdx.x;
  const int wave = tid>>6, lane = tid&63;
  const int wg = xcd_swizzle(blockIdx.x, gridDim.x);
  const int tn = wg % nx, tm = wg / nx;
  const int wm = wave>>1, wn = wave&1;
  const int fr = lane & 15, l4 = lane>>4;

  f32x4v acc[4][6];
  #pragma unroll
  for (int i=0;i<4;++i)
    #pragma unroll
    for (int j=0;j<6;++j)
      #pragma unroll
      for (int e=0;e<4;++e) acc[i][j][e] = 0.f;

  const int lr8 = lane>>3, lc8 = lane&7;
  const size_t lane_src = (size_t)lr8*K + (size_t)((lc8 ^ lr8)*16);
  const unsigned char* gA = A + ((size_t)tm*128 + wave*32)*K + lane_src;
  const unsigned char* gB = B + ((size_t)tn*192 + wave*48)*K + lane_src;

  auto stage = [&](int buf, int koff){
    #pragma unroll
    for (int j=0;j<4;++j)
      gload16(gA + (size_t)(j*8)*K + koff, &As[buf][(wave*32 + j*8)*128]);
    #pragma unroll
    for (int j=0;j<6;++j)
      gload16(gB + (size_t)(j*8)*K + koff, &Bs[buf][(wave*48 + j*8)*128]);
  };

  stage(0, 0);

  int roff[4];
  #pragma unroll
  for (int kk=0;kk<4;++kk)
    roff[kk] = (((kk*2 + (l4>>1)) ^ (fr & 7))<<4) + ((l4&1)<<3);

  #pragma unroll 2
  for (int kt=0; kt<KTB; ++kt){
    asm volatile("s_waitcnt vmcnt(0) lgkmcnt(0)" ::: "memory");
    __builtin_amdgcn_s_barrier();
    if (kt+1 < KTB) stage((kt+1)&1, (kt+1)*128);
    const unsigned char* Ab = As[kt&1];
    const unsigned char* Bb = Bs[kt&1];
    long af[4][4], bfr[6][4];
    #pragma unroll
    for (int i=0;i<4;++i){
      int ra = (wm*64 + i*16 + fr)*128;
      #pragma unroll
      for (int kk=0;kk<4;++kk) af[i][kk] = *(const long*)&Ab[ra + roff[kk]];
    }
    #pragma unroll
    for (int i=0;i<6;++i){
      int rb = (wn*96 + i*16 + fr)*128;
      #pragma unroll
      for (int kk=0;kk<4;++kk) bfr[i][kk] = *(const long*)&Bb[rb + roff[kk]];
    }
    #pragma unroll
    for (int mi=0;mi<4;++mi)
      #pragma unroll
      for (int ni=0;ni<6;++ni)
        #pragma unroll
        for (int kk=0;kk<4;++kk)
          acc[mi][ni] = __builtin_amdgcn_mfma_f32_16x16x32_fp8_fp8(af[mi][kk], bfr[ni][kk], acc[mi][ni], 0,0,0);
  }

  #pragma unroll
  for (int mi=0;mi<4;++mi){
    #pragma unroll
    for (int ni=0;ni<6;++ni){
      int col = tn*192 + wn*96 + ni*16 + fr;
      float bv = bias[col];
      int rowb = tm*128 + wm*64 + mi*16 + l4*4;
      #pragma unroll
      for (int r=0;r<4;++r){
        size_t idx = (size_t)(rowb+r)*N + col;
        float v = acc[mi][ni][r] + bv;
        if (EPI==1){
          ((unsigned char*)outp)[idx] = f2fp8(gelu_f(v));
        } else {
          ((float*)outp)[idx] = v + resid[idx];
        }
      }
    }
  }
}

// ------- FUSED proj GEMM + residual + window-reverse scatter + LN2 (ln2 -> fp8) -------
template<int KT>
__global__ __launch_bounds__(512, 1)
void k_projln2(const bf16* __restrict__ A, const bf16* __restrict__ B,
               const float* __restrict__ bias, const float* __restrict__ x,
               const float* __restrict__ g, const float* __restrict__ b2,
               float* __restrict__ outx, unsigned char* __restrict__ ln2,
               long tbase, long lnbase)
{
  constexpr int K = KT*32;   // 384
  __shared__ __align__(16) bf16 As[2][128*32];
  __shared__ __align__(16) bf16 Bs[2][384*32];
  __shared__ float redS[128][4];
  __shared__ float redQ[128][4];
  const int tid = threadIdx.x;
  const int wave = tid>>6, lane = tid&63;
  const int tm = xcd_swizzle(blockIdx.x, gridDim.x);
  const int wm = wave>>2, wn = wave&3;
  const int fr = lane & 15, l4 = lane>>4;

  f32x4v acc[4][6];
  #pragma unroll
  for (int i=0;i<4;++i)
    #pragma unroll
    for (int j=0;j<6;++j)
      #pragma unroll
      for (int e=0;e<4;++e) acc[i][j][e] = 0.f;

  const int srow0 = lane>>2;
  const int scol_sw = (((lane&3) ^ ((lane>>3)&3)))*8;
  const bf16* gA = A + ((size_t)tm*128 + wave*16 + srow0)*K + scol_sw;
  const bf16* gB = B + ((size_t)(wave*16) + srow0)*K + scol_sw;

  auto stage = [&](int buf, int koff){
    gload16(gA + koff, &As[buf][wave*512]);
    #pragma unroll
    for (int j=0;j<3;++j)
      gload16(gB + (size_t)(128*j)*K + koff, &Bs[buf][(j*128 + wave*16)*32]);
  };

  stage(0, 0);
  const int fko_sw = ((l4 ^ ((fr>>1)&3)))*8;

  #pragma unroll 2
  for (int kt=0; kt<KT; ++kt){
    asm volatile("s_waitcnt vmcnt(0) lgkmcnt(0)" ::: "memory");
    __builtin_amdgcn_s_barrier();
    if (kt+1 < KT) stage((kt+1)&1, (kt+1)*32);
    const bf16* Ab = As[kt&1];
    const bf16* Bb = Bs[kt&1];
    s16x8 af[4], bfr[6];
    #pragma unroll
    for (int i=0;i<6;++i)
      bfr[i] = *(const s16x8*)&Bb[(wn*96 + i*16 + fr)*32 + fko_sw];
    #pragma unroll
    for (int i=0;i<4;++i)
      af[i] = *(const s16x8*)&Ab[(wm*64 + i*16 + fr)*32 + fko_sw];
    #pragma unroll
    for (int mi=0;mi<4;++mi)
      #pragma unroll
      for (int ni=0;ni<6;++ni)
        acc[mi][ni] = __builtin_amdgcn_mfma_f32_16x16x32_bf16(af[mi], bfr[ni], acc[mi][ni], 0,0,0);
    __builtin_amdgcn_s_barrier();
  }

  float bv[6];
  #pragma unroll
  for (int ni=0;ni<6;++ni) bv[ni] = bias[wn*96 + ni*16 + fr];

  long nr[4][4];
  #pragma unroll
  for (int mi=0;mi<4;++mi){
    #pragma unroll
    for (int r=0;r<4;++r){
      int lrow = wm*64 + mi*16 + l4*4 + r;
      int ti = (int)(tbase + (long)tm*128 + lrow);
      int win = ti/98, n = ti - win*98;
      int batch = win>>8;
      int wq = win&7, hq = (win>>3)&7, dq = (win>>6)&3;
      int dr = n/49, rem = n - dr*49, hr = rem/7, wr = rem - hr*7;
      int d = dq*2+dr, h = hq*7+hr, w = wq*7+wr;
      int sd = (d+1)&7;
      int sh = h+3; if (sh>=56) sh-=56;
      int sw = w+3; if (sw>=56) sw-=56;
      long nrow = (long)batch*25088 + (long)(sd*56+sh)*56 + sw;
      nr[mi][r] = nrow;
      const float* xrow = x + (size_t)nrow*384;
      float* orow = outx + (size_t)nrow*384;
      float s = 0.f, q = 0.f;
      #pragma unroll
      for (int ni=0;ni<6;++ni){
        int col = wn*96 + ni*16 + fr;
        float hvl = acc[mi][ni][r] + bv[ni] + xrow[col];
        orow[col] = hvl;
        acc[mi][ni][r] = hvl;
        s += hvl; q += hvl*hvl;
      }
      s += __shfl_xor(s,1); q += __shfl_xor(q,1);
      s += __shfl_xor(s,2); q += __shfl_xor(q,2);
      s += __shfl_xor(s,4); q += __shfl_xor(q,4);
      s += __shfl_xor(s,8); q += __shfl_xor(q,8);
      if (fr == 0){ redS[lrow][wn] = s; redQ[lrow][wn] = q; }
    }
  }
  __syncthreads();
  float gv[6], b2v[6];
  #pragma unroll
  for (int ni=0;ni<6;++ni){
    int col = wn*96 + ni*16 + fr;
    gv[ni] = g[col]; b2v[ni] = b2[col];
  }
  #pragma unroll
  for (int mi=0;mi<4;++mi){
    #pragma unroll
    for (int r=0;r<4;++r){
      int lrow = wm*64 + mi*16 + l4*4 + r;
      float S = redS[lrow][0] + redS[lrow][1] + redS[lrow][2] + redS[lrow][3];
      float Q = redQ[lrow][0] + redQ[lrow][1] + redQ[lrow][2] + redQ[lrow][3];
      float mu = S*(1.f/384.f);
      float var = Q*(1.f/384.f) - mu*mu;
      float rstd = rsqrtf(var + 1e-5f);
      unsigned char* lrowp = ln2 + (size_t)(nr[mi][r] - lnbase)*384;
      #pragma unroll
      for (int ni=0;ni<6;++ni){
        int col = wn*96 + ni*16 + fr;
        lrowp[col] = f2fp8((acc[mi][ni][r] - mu)*rstd*gv[ni] + b2v[ni]);
      }
    }
  }
}

// ------- MFMA windowed attention (qkv row stride = qs) -------
// R18 conflict/VALU fixes + __launch_bounds__(256,8): pin <=64 VGPR so 8 waves/SIMD
// (R18's 68 VGPR dropped occupancy 41->31% and regressed despite lower conflicts).
__global__ __launch_bounds__(256, 8)
void k_attn(const bf16* __restrict__ qkv, const float* __restrict__ comb,
            bf16* __restrict__ outp, int qs)
{
  const int wg   = xcd_swizzle(blockIdx.x, gridDim.x);
  const int head = wg % 12;
  const int win  = wg / 12;
  const int tid  = threadIdx.x;
  const int wave = tid>>6;
  const int lane = tid&63;
  const int l15 = lane & 15, l4 = lane>>4;
  __shared__ __align__(16) bf16 Vt[32*136];
  __shared__ __align__(16) bf16 P_buf[4][16*40];

  const int wq = win&7, hq=(win>>3)&7, dq=(win>>6)&3;
  const int cls = ((dq==3)?4:0) | ((hq==7)?2:0) | ((wq==7)?1:0);
  const float* combbase = comb + (size_t)(cls*12+head)*16384;
  const bf16* qkvw_ = qkv + (size_t)win*98*qs;

  // V transpose staging: unit u -> token m = u&127 (contiguous across wave ->
  // writes hit all 32 banks, 2-way = free), d0-chunk = (u>>7)*8.
  for (int u = tid; u < 512; u += 256){
    int m = u & 127, d0 = (u>>7)*8;
    int mc = m>97 ? 97 : m;
    s16x8 v = *(const s16x8*)(qkvw_ + (size_t)mc*qs + 768 + head*32 + d0);
    #pragma unroll
    for (int e=0;e<8;++e){ short sv = v[e]; Vt[(d0+e)*136 + m] = *(bf16*)&sv; }
  }
  s16x8 kb[8];
  #pragma unroll
  for (int j=0;j<8;++j){
    int tok = j*16 + l15; if (tok>97) tok = 97;
    kb[j] = *(const s16x8*)(qkvw_ + (size_t)tok*qs + 384 + head*32 + l4*8);
  }
  __syncthreads();

  const int c0 = wave*32;
  bf16* Pw = P_buf[wave];
  const int pswz = (l15>>2)&3;   // read-side XOR key for row l15
  #pragma unroll
  for (int mi=0;mi<2;++mi){
    int q = c0 + mi*16 + l15; if (q>97) q=97;
    s16x8 aq = *(const s16x8*)(qkvw_ + (size_t)q*qs + head*32 + l4*8);
    // comb C-init: rows (c0+mi*16+l4*4)+0..3, col j*16+l15 -> one f32x4 per j
    const float* cb = combbase + ((size_t)(wave*8 + mi*4 + l4)*128 + l15)*4;
    f32x4v s[8];
    #pragma unroll
    for (int j=0;j<8;++j){
      f32x4v ci = *(const f32x4v*)(cb + j*64);
      s[j] = __builtin_amdgcn_mfma_f32_16x16x32_bf16(aq, kb[j], ci, 0,0,0);
    }
    float rinv[4];
    #pragma unroll
    for (int r=0;r<4;++r){
      float mx = s[0][r];
      #pragma unroll
      for (int j=1;j<8;++j) mx = fmaxf(mx, s[j][r]);
      mx = fmaxf(mx, __shfl_xor(mx,1));
      mx = fmaxf(mx, __shfl_xor(mx,2));
      mx = fmaxf(mx, __shfl_xor(mx,4));
      mx = fmaxf(mx, __shfl_xor(mx,8));
      float sum = 0.f;
      #pragma unroll
      for (int j=0;j<8;++j){ float e = __expf(s[j][r]-mx); s[j][r]=e; sum+=e; }
      sum += __shfl_xor(sum,1);
      sum += __shfl_xor(sum,2);
      sum += __shfl_xor(sum,4);
      sum += __shfl_xor(sum,8);
      rinv[r] = 1.f/sum;
    }
    f32x4v oacc[2] = {{0.f,0.f,0.f,0.f},{0.f,0.f,0.f,0.f}};
    #pragma unroll
    for (int ks=0; ks<4; ++ks){
      // P scatter, chunk-XOR swizzled: row = l4*4+r ((row>>2)&3 == l4),
      // col chunk c stored at slot c ^ l4.
      #pragma unroll
      for (int jj=0;jj<2;++jj)
        #pragma unroll
        for (int r=0;r<4;++r){
          int col = jj*16 + l15;
          int slot = ((col>>3) ^ l4)*8 + (col&7);
          Pw[(l4*4+r)*40 + slot] = f2bf(s[ks*2+jj][r]);
        }
      s16x8 pa = *(const s16x8*)&Pw[l15*40 + (l4 ^ pswz)*8];
      #pragma unroll
      for (int ni=0;ni<2;++ni){
        s16x8 vb = *(const s16x8*)&Vt[(ni*16+l15)*136 + ks*32 + l4*8];
        oacc[ni] = __builtin_amdgcn_mfma_f32_16x16x32_bf16(pa, vb, oacc[ni], 0,0,0);
      }
    }
    #pragma unroll
    for (int r=0;r<4;++r){
      int qo = c0 + mi*16 + l4*4 + r;
      if (qo < 98){
        bf16* orow = outp + ((size_t)win*98 + qo)*384 + head*32;
        #pragma unroll
        for (int ni=0;ni<2;++ni)
          orow[ni*16+l15] = f2bf(oacc[ni][r]*rinv[r]);
      }
    }
  }
}

extern "C" void kernel_launch(void* const* d_in, const int* in_sizes, int n_in,
                              void* d_out, int out_size, void* d_ws, size_t ws_size,
                              hipStream_t stream)
{
  const float* x     = (const float*)d_in[0];
  const float* n1g   = (const float*)d_in[1];
  const float* n1b   = (const float*)d_in[2];
  const float* qkvw  = (const float*)d_in[3];
  const float* qkvbv = (const float*)d_in[4];
  const float* rpb   = (const float*)d_in[5];
  const float* projw = (const float*)d_in[6];
  const float* projb = (const float*)d_in[7];
  const float* n2g   = (const float*)d_in[8];
  const float* n2b   = (const float*)d_in[9];
  const float* fc1w  = (const float*)d_in[10];
  const float* fc1b  = (const float*)d_in[11];
  const float* fc2w  = (const float*)d_in[12];
  const float* fc2b  = (const float*)d_in[13];
  float* out = (float*)d_out;

  char* ws = (char*)d_ws;
  size_t off = 0;
  auto alloc = [&](size_t bytes)->char*{
    char* p = ws + off; off += (bytes + 255) & ~(size_t)255; return p;
  };
  bf16*  wbf   = (bf16*)alloc((size_t)589824*2);            // qkv | proj (bf16)
  bf16*  wqkv  = wbf;
  bf16*  wproj = wbf + 442368;
  unsigned char* wfc1q = (unsigned char*)alloc(589824);     // fc1 fp8
  unsigned char* wfc2q = (unsigned char*)alloc(589824);     // fc2 fp8
  float* comb  = (float*)alloc((size_t)96*128*128*4);

  k_f2bf2<<<(589824+255)/256,256,0,stream>>>(qkvw, projw, wbf);
  k_f2fp8w<<<(589824+255)/256,256,0,stream>>>(fc1w, fc2w, wfc1q, wfc2q);
  k_comb<<<6144,256,0,stream>>>(rpb, comb);

  const size_t fused_need = off
      + (((size_t)100352*384*2  + 255) & ~(size_t)255)   // xw
      + (((size_t)100352*1536*2 + 255) & ~(size_t)255)   // bufA (qkv bf16 / fc1-out fp8)
      + (((size_t)100352*384    + 255) & ~(size_t)255);  // ln2 (fp8)
  if (ws_size >= fused_need){
    bf16* xw    = (bf16*)alloc((size_t)100352*384*2);
    bf16* bufA  = (bf16*)alloc((size_t)100352*1536*2);
    unsigned char* ln2 = (unsigned char*)alloc((size_t)100352*384);
    bf16* attno = bufA + (size_t)100352*1152;            // tail of bufA (bf16 region)
    unsigned char* mlp = (unsigned char*)bufA;           // fc1 fp8 output

    k_ln1<<<25088,256,0,stream>>>(x, n1g, n1b, xw, 0L);
    k_gemm192<3,6><<<784*6,256,0,stream>>>(xw, wqkv, qkvbv, nullptr, bufA, 1152, 6);
    k_attn<<<12*1024,256,0,stream>>>(bufA, comb, attno, 1152);
    k_projln2<12><<<784,512,0,stream>>>(attno, wproj, projb, x, n2g, n2b, out, ln2, 0L, 0L);
    k_gemm_fp8<1,3><<<784*8,256,0,stream>>>(ln2, wfc1q, fc1b, nullptr, mlp, 1536, 8);
    k_gemm_fp8<2,12><<<784*2,256,0,stream>>>(mlp, wfc2q, fc2b, out, (void*)out, 384, 2);
  } else {
    bf16* xw    = (bf16*)alloc((size_t)25088*384*2);
    bf16* bufA  = (bf16*)alloc((size_t)25088*1536*2);
    unsigned char* ln2 = (unsigned char*)alloc((size_t)25088*384);
    bf16* attno = bufA + (size_t)25088*1152;
    unsigned char* mlp = (unsigned char*)bufA;
    for (int b=0; b<4; ++b){
      long tbase = (long)b*25088;
      k_ln1<<<6272,256,0,stream>>>(x, n1g, n1b, xw, tbase);
      k_gemm192<3,6><<<196*6,256,0,stream>>>(xw, wqkv, qkvbv, nullptr, bufA, 1152, 6);
      k_attn<<<12*256,256,0,stream>>>(bufA, comb, attno, 1152);
      k_projln2<12><<<196,512,0,stream>>>(attno, wproj, projb, x, n2g, n2b, out, ln2, tbase, tbase);
      k_gemm_fp8<1,3><<<196*8,256,0,stream>>>(ln2, wfc1q, fc1b, nullptr, mlp, 1536, 8);
      float* resid = out + (size_t)b*25088*384;
      k_gemm_fp8<2,12><<<196*2,256,0,stream>>>(mlp, wfc2q, fc2b, resid, (void*)resid, 384, 2);
    }
  }
}

// Round 20
// 846.023 us; speedup vs baseline: 1.2023x; 1.2023x over previous
//
#include <hip/hip_runtime.h>
#include <hip/hip_bf16.h>
#include <hip/hip_fp8.h>
#include <cmath>

typedef __hip_bfloat16 bf16;
typedef __attribute__((ext_vector_type(8))) short s16x8;
typedef __attribute__((ext_vector_type(4))) float f32x4v;

__device__ __forceinline__ float bf2f(bf16 v){ return __bfloat162float(v); }
__device__ __forceinline__ bf16  f2bf(float v){ return __float2bfloat16(v); }
__device__ __forceinline__ unsigned char f2fp8(float v){
  __hip_fp8_e4m3 q(v);
  return *reinterpret_cast<unsigned char*>(&q);
}

__device__ __forceinline__ void gload16(const void* g, void* l){
  __builtin_amdgcn_global_load_lds((const __attribute__((address_space(1))) void*)g,
                                   (__attribute__((address_space(3))) void*)l,
                                   16, 0, 0);
}

// bijective XCD-chunk swizzle (m204)
__device__ __forceinline__ int xcd_swizzle(int bid, int nb){
  int q = nb >> 3, r = nb & 7;
  int xcd = bid & 7, idx = bid >> 3;
  return (xcd < r) ? (xcd*(q+1) + idx) : (r + xcd*q + idx);
}

// tanh-form GELU
__device__ __forceinline__ float gelu_f(float v){
  float y = 0.797884561f*(v + 0.044715f*v*v*v);
  float e = __expf(-2.f*y);
  return v * __builtin_amdgcn_rcpf(1.f + e);
}

// ---------------- merged weight fp32 -> bf16 (qkv | proj) ----------------
__global__ void k_f2bf2(const float* __restrict__ s0, const float* __restrict__ s1,
                        bf16* __restrict__ out){
  int i = blockIdx.x*256 + threadIdx.x;
  if (i >= 589824) return;
  out[i] = f2bf(i < 442368 ? s0[i] : s1[i - 442368]);
}
// fc1 | fc2 fp32 -> fp8 (589824 each)
__global__ void k_f2fp8w(const float* __restrict__ s0, const float* __restrict__ s1,
                         unsigned char* __restrict__ o0, unsigned char* __restrict__ o1){
  int i = blockIdx.x*256 + threadIdx.x;
  if (i >= 589824) return;
  o0[i] = f2fp8(s0[i]);
  o1[i] = f2fp8(s1[i]);
}

// ------- combined bias+mask table (f32): comb[cls(8)][head(12)][row 128][col 128] -------
__global__ void k_comb(const float* __restrict__ rpb, float* __restrict__ comb){
  int idx = blockIdx.x*256 + threadIdx.x;        // 96*128*128
  int col = idx & 127, row = (idx>>7)&127, clshead = idx>>14;
  int cls = clshead/12, head = clshead - cls*12;
  float v;
  if (row >= 98) v = 0.f;
  else if (col >= 98) v = -10000.f;
  else {
    int qd = row/49, qr = row%49, qh = qr/7, qw = qr%7;
    int kd = col/49, kr = col%49, kh = kr/7, kw = kr%7;
    int pbq = qd*169 + qh*13 + qw;
    int pbk = kd*169 + kh*13 + kw;
    int lq, lk;
    {
      int ld = (cls&4) ? (qd==0?1:2) : 0;
      int lh = (cls&2) ? (qh<4?1:2) : 0;
      int lw = (cls&1) ? (qw<4?1:2) : 0;
      lq = ld*9+lh*3+lw;
    }
    {
      int ld = (cls&4) ? (kd==0?1:2) : 0;
      int lh = (cls&2) ? (kh<4?1:2) : 0;
      int lw = (cls&1) ? (kw<4?1:2) : 0;
      lk = ld*9+lh*3+lw;
    }
    float bias = rpb[(pbq-pbk+253)*12 + head];
    v = bias + ((lq!=lk) ? -100.f : 0.f);
  }
  comb[idx] = v;
}

// ------- LN1 + cyclic shift + window partition (one wave per token) -------
__global__ __launch_bounds__(256)
void k_ln1(const float* __restrict__ x, const float* __restrict__ g,
           const float* __restrict__ b, bf16* __restrict__ xw, long tbase)
{
  int tl = blockIdx.x*4 + (threadIdx.x>>6);
  long t = tbase + tl;
  int lane = threadIdx.x & 63;
  int win = (int)(t / 98), n = (int)(t % 98);
  int batch = win>>8;
  int wq = win & 7, hq = (win>>3)&7, dq = (win>>6)&3;
  int dr = n/49, rem = n%49, hr = rem/7, wr = rem%7;
  int d = dq*2+dr, h = hq*7+hr, w = wq*7+wr;
  int sd = (d+1)&7;
  int sh = h+3; if (sh>=56) sh-=56;
  int sw = w+3; if (sw>=56) sw-=56;
  const float* row = x + ((size_t)(((batch*8+sd)*56+sh)*56+sw))*384;
  float v[6]; float s=0.f, ss=0.f;
  int c0 = lane*6;
  #pragma unroll
  for (int i=0;i<6;++i){ float f = row[c0+i]; v[i]=f; s+=f; ss+=f*f; }
  #pragma unroll
  for (int o=32;o>0;o>>=1){ s += __shfl_xor(s,o); ss += __shfl_xor(ss,o); }
  float mu = s*(1.f/384.f);
  float var = ss*(1.f/384.f) - mu*mu;
  float rstd = rsqrtf(var + 1e-5f);
  bf16* orow = xw + (size_t)tl*384;
  #pragma unroll
  for (int i=0;i<6;++i){ int c=c0+i; orow[c] = f2bf((v[i]-mu)*rstd*g[c] + b[c]); }
}

// ------- bf16 MFMA GEMM: tile 128x192, wave tile 64x96, BK=64 (R16 best) -------
// EPI: 0 bias->bf16; 3 bias, scale cols<384 ->bf16
template<int EPI, int KT>   // KT = K/64
__global__ __launch_bounds__(256, 2)
void k_gemm192(const bf16* __restrict__ A, const bf16* __restrict__ B,
               const float* __restrict__ bias, const float* __restrict__ resid,
               void* __restrict__ outp, int N, int nx)
{
  constexpr int K = KT*64;
  __shared__ __align__(16) bf16 As[2][128*64];   // 32 KB
  __shared__ __align__(16) bf16 Bs[2][192*64];   // 48 KB
  const int tid = threadIdx.x;
  const int wave = tid>>6, lane = tid&63;
  const int wg = xcd_swizzle(blockIdx.x, gridDim.x);
  const int tn = wg % nx, tm = wg / nx;
  const int wm = wave>>1, wn = wave&1;
  const int fr = lane & 15, l4 = lane>>4;

  f32x4v acc[4][6];
  #pragma unroll
  for (int i=0;i<4;++i)
    #pragma unroll
    for (int j=0;j<6;++j)
      #pragma unroll
      for (int e=0;e<4;++e) acc[i][j][e] = 0.f;

  const int lr8 = lane>>3, lc8 = lane&7;
  const size_t lane_src = (size_t)lr8*K + (size_t)((lc8 ^ lr8)*8);
  const bf16* gA = A + ((size_t)tm*128 + wave*32)*K + lane_src;
  const bf16* gB = B + ((size_t)tn*192 + wave*48)*K + lane_src;

  auto stage = [&](int buf, int koff){
    #pragma unroll
    for (int j=0;j<4;++j)
      gload16(gA + (size_t)(j*8)*K + koff, &As[buf][(wave*32 + j*8)*64]);
    #pragma unroll
    for (int j=0;j<6;++j)
      gload16(gB + (size_t)(j*8)*K + koff, &Bs[buf][(wave*48 + j*8)*64]);
  };

  stage(0, 0);
  const int slot0 = (l4 ^ (fr & 7)) * 8;

  #pragma unroll 2
  for (int kt=0; kt<KT; ++kt){
    asm volatile("s_waitcnt vmcnt(0) lgkmcnt(0)" ::: "memory");
    __builtin_amdgcn_s_barrier();
    if (kt+1 < KT) stage((kt+1)&1, (kt+1)*64);
    const bf16* Ab = As[kt&1];
    const bf16* Bb = Bs[kt&1];
    s16x8 af[4][2], bfr[6][2];
    #pragma unroll
    for (int i=0;i<4;++i){
      int ra = (wm*64 + i*16 + fr)*64;
      af[i][0] = *(const s16x8*)&Ab[ra + slot0];
      af[i][1] = *(const s16x8*)&Ab[ra + (slot0^32)];
    }
    #pragma unroll
    for (int i=0;i<6;++i){
      int rb = (wn*96 + i*16 + fr)*64;
      bfr[i][0] = *(const s16x8*)&Bb[rb + slot0];
      bfr[i][1] = *(const s16x8*)&Bb[rb + (slot0^32)];
    }
    #pragma unroll
    for (int mi=0;mi<4;++mi)
      #pragma unroll
      for (int ni=0;ni<6;++ni)
        #pragma unroll
        for (int kk=0;kk<2;++kk)
          acc[mi][ni] = __builtin_amdgcn_mfma_f32_16x16x32_bf16(af[mi][kk], bfr[ni][kk], acc[mi][ni], 0,0,0);
  }

  #pragma unroll
  for (int mi=0;mi<4;++mi){
    #pragma unroll
    for (int ni=0;ni<6;++ni){
      int col = tn*192 + wn*96 + ni*16 + fr;
      float bv = bias[col];
      int rowb = tm*128 + wm*64 + mi*16 + l4*4;
      #pragma unroll
      for (int r=0;r<4;++r){
        size_t idx = (size_t)(rowb+r)*N + col;
        float v = acc[mi][ni][r] + bv;
        if (EPI==0){
          ((bf16*)outp)[idx] = f2bf(v);
        } else {
          if (col < 384) v *= 0.17677669529663687f;
          ((bf16*)outp)[idx] = f2bf(v);
        }
      }
    }
  }
}

// ------- fp8 MFMA GEMM: tile 128x192, wave tile 64x96, BK=128 bytes (R17) -------
// EPI: 1 bias+GELU -> fp8; 2 bias+resid -> f32
template<int EPI, int KTB>   // KTB = K/128
__global__ __launch_bounds__(256, 2)
void k_gemm_fp8(const unsigned char* __restrict__ A, const unsigned char* __restrict__ B,
                const float* __restrict__ bias, const float* __restrict__ resid,
                void* __restrict__ outp, int N, int nx)
{
  constexpr int K = KTB*128;                       // bytes per row
  __shared__ __align__(16) unsigned char As[2][128*128];   // 32 KB
  __shared__ __align__(16) unsigned char Bs[2][192*128];   // 48 KB
  const int tid = threadIdx.x;
  const int wave = tid>>6, lane = tid&63;
  const int wg = xcd_swizzle(blockIdx.x, gridDim.x);
  const int tn = wg % nx, tm = wg / nx;
  const int wm = wave>>1, wn = wave&1;
  const int fr = lane & 15, l4 = lane>>4;

  f32x4v acc[4][6];
  #pragma unroll
  for (int i=0;i<4;++i)
    #pragma unroll
    for (int j=0;j<6;++j)
      #pragma unroll
      for (int e=0;e<4;++e) acc[i][j][e] = 0.f;

  const int lr8 = lane>>3, lc8 = lane&7;
  const size_t lane_src = (size_t)lr8*K + (size_t)((lc8 ^ lr8)*16);
  const unsigned char* gA = A + ((size_t)tm*128 + wave*32)*K + lane_src;
  const unsigned char* gB = B + ((size_t)tn*192 + wave*48)*K + lane_src;

  auto stage = [&](int buf, int koff){
    #pragma unroll
    for (int j=0;j<4;++j)
      gload16(gA + (size_t)(j*8)*K + koff, &As[buf][(wave*32 + j*8)*128]);
    #pragma unroll
    for (int j=0;j<6;++j)
      gload16(gB + (size_t)(j*8)*K + koff, &Bs[buf][(wave*48 + j*8)*128]);
  };

  stage(0, 0);

  int roff[4];
  #pragma unroll
  for (int kk=0;kk<4;++kk)
    roff[kk] = (((kk*2 + (l4>>1)) ^ (fr & 7))<<4) + ((l4&1)<<3);

  #pragma unroll 2
  for (int kt=0; kt<KTB; ++kt){
    asm volatile("s_waitcnt vmcnt(0) lgkmcnt(0)" ::: "memory");
    __builtin_amdgcn_s_barrier();
    if (kt+1 < KTB) stage((kt+1)&1, (kt+1)*128);
    const unsigned char* Ab = As[kt&1];
    const unsigned char* Bb = Bs[kt&1];
    long af[4][4], bfr[6][4];
    #pragma unroll
    for (int i=0;i<4;++i){
      int ra = (wm*64 + i*16 + fr)*128;
      #pragma unroll
      for (int kk=0;kk<4;++kk) af[i][kk] = *(const long*)&Ab[ra + roff[kk]];
    }
    #pragma unroll
    for (int i=0;i<6;++i){
      int rb = (wn*96 + i*16 + fr)*128;
      #pragma unroll
      for (int kk=0;kk<4;++kk) bfr[i][kk] = *(const long*)&Bb[rb + roff[kk]];
    }
    #pragma unroll
    for (int mi=0;mi<4;++mi)
      #pragma unroll
      for (int ni=0;ni<6;++ni)
        #pragma unroll
        for (int kk=0;kk<4;++kk)
          acc[mi][ni] = __builtin_amdgcn_mfma_f32_16x16x32_fp8_fp8(af[mi][kk], bfr[ni][kk], acc[mi][ni], 0,0,0);
  }

  #pragma unroll
  for (int mi=0;mi<4;++mi){
    #pragma unroll
    for (int ni=0;ni<6;++ni){
      int col = tn*192 + wn*96 + ni*16 + fr;
      float bv = bias[col];
      int rowb = tm*128 + wm*64 + mi*16 + l4*4;
      #pragma unroll
      for (int r=0;r<4;++r){
        size_t idx = (size_t)(rowb+r)*N + col;
        float v = acc[mi][ni][r] + bv;
        if (EPI==1){
          ((unsigned char*)outp)[idx] = f2fp8(gelu_f(v));
        } else {
          ((float*)outp)[idx] = v + resid[idx];
        }
      }
    }
  }
}

// ------- FUSED proj GEMM + residual + window-reverse scatter + LN2 (ln2 -> fp8) -------
template<int KT>
__global__ __launch_bounds__(512, 1)
void k_projln2(const bf16* __restrict__ A, const bf16* __restrict__ B,
               const float* __restrict__ bias, const float* __restrict__ x,
               const float* __restrict__ g, const float* __restrict__ b2,
               float* __restrict__ outx, unsigned char* __restrict__ ln2,
               long tbase, long lnbase)
{
  constexpr int K = KT*32;   // 384
  __shared__ __align__(16) bf16 As[2][128*32];
  __shared__ __align__(16) bf16 Bs[2][384*32];
  __shared__ float redS[128][4];
  __shared__ float redQ[128][4];
  const int tid = threadIdx.x;
  const int wave = tid>>6, lane = tid&63;
  const int tm = xcd_swizzle(blockIdx.x, gridDim.x);
  const int wm = wave>>2, wn = wave&3;
  const int fr = lane & 15, l4 = lane>>4;

  f32x4v acc[4][6];
  #pragma unroll
  for (int i=0;i<4;++i)
    #pragma unroll
    for (int j=0;j<6;++j)
      #pragma unroll
      for (int e=0;e<4;++e) acc[i][j][e] = 0.f;

  const int srow0 = lane>>2;
  const int scol_sw = (((lane&3) ^ ((lane>>3)&3)))*8;
  const bf16* gA = A + ((size_t)tm*128 + wave*16 + srow0)*K + scol_sw;
  const bf16* gB = B + ((size_t)(wave*16) + srow0)*K + scol_sw;

  auto stage = [&](int buf, int koff){
    gload16(gA + koff, &As[buf][wave*512]);
    #pragma unroll
    for (int j=0;j<3;++j)
      gload16(gB + (size_t)(128*j)*K + koff, &Bs[buf][(j*128 + wave*16)*32]);
  };

  stage(0, 0);
  const int fko_sw = ((l4 ^ ((fr>>1)&3)))*8;

  #pragma unroll 2
  for (int kt=0; kt<KT; ++kt){
    asm volatile("s_waitcnt vmcnt(0) lgkmcnt(0)" ::: "memory");
    __builtin_amdgcn_s_barrier();
    if (kt+1 < KT) stage((kt+1)&1, (kt+1)*32);
    const bf16* Ab = As[kt&1];
    const bf16* Bb = Bs[kt&1];
    s16x8 af[4], bfr[6];
    #pragma unroll
    for (int i=0;i<6;++i)
      bfr[i] = *(const s16x8*)&Bb[(wn*96 + i*16 + fr)*32 + fko_sw];
    #pragma unroll
    for (int i=0;i<4;++i)
      af[i] = *(const s16x8*)&Ab[(wm*64 + i*16 + fr)*32 + fko_sw];
    #pragma unroll
    for (int mi=0;mi<4;++mi)
      #pragma unroll
      for (int ni=0;ni<6;++ni)
        acc[mi][ni] = __builtin_amdgcn_mfma_f32_16x16x32_bf16(af[mi], bfr[ni], acc[mi][ni], 0,0,0);
    __builtin_amdgcn_s_barrier();
  }

  float bv[6];
  #pragma unroll
  for (int ni=0;ni<6;++ni) bv[ni] = bias[wn*96 + ni*16 + fr];

  long nr[4][4];
  #pragma unroll
  for (int mi=0;mi<4;++mi){
    #pragma unroll
    for (int r=0;r<4;++r){
      int lrow = wm*64 + mi*16 + l4*4 + r;
      int ti = (int)(tbase + (long)tm*128 + lrow);
      int win = ti/98, n = ti - win*98;
      int batch = win>>8;
      int wq = win&7, hq = (win>>3)&7, dq = (win>>6)&3;
      int dr = n/49, rem = n - dr*49, hr = rem/7, wr = rem - hr*7;
      int d = dq*2+dr, h = hq*7+hr, w = wq*7+wr;
      int sd = (d+1)&7;
      int sh = h+3; if (sh>=56) sh-=56;
      int sw = w+3; if (sw>=56) sw-=56;
      long nrow = (long)batch*25088 + (long)(sd*56+sh)*56 + sw;
      nr[mi][r] = nrow;
      const float* xrow = x + (size_t)nrow*384;
      float* orow = outx + (size_t)nrow*384;
      float s = 0.f, q = 0.f;
      #pragma unroll
      for (int ni=0;ni<6;++ni){
        int col = wn*96 + ni*16 + fr;
        float hvl = acc[mi][ni][r] + bv[ni] + xrow[col];
        orow[col] = hvl;
        acc[mi][ni][r] = hvl;
        s += hvl; q += hvl*hvl;
      }
      s += __shfl_xor(s,1); q += __shfl_xor(q,1);
      s += __shfl_xor(s,2); q += __shfl_xor(q,2);
      s += __shfl_xor(s,4); q += __shfl_xor(q,4);
      s += __shfl_xor(s,8); q += __shfl_xor(q,8);
      if (fr == 0){ redS[lrow][wn] = s; redQ[lrow][wn] = q; }
    }
  }
  __syncthreads();
  float gv[6], b2v[6];
  #pragma unroll
  for (int ni=0;ni<6;++ni){
    int col = wn*96 + ni*16 + fr;
    gv[ni] = g[col]; b2v[ni] = b2[col];
  }
  #pragma unroll
  for (int mi=0;mi<4;++mi){
    #pragma unroll
    for (int r=0;r<4;++r){
      int lrow = wm*64 + mi*16 + l4*4 + r;
      float S = redS[lrow][0] + redS[lrow][1] + redS[lrow][2] + redS[lrow][3];
      float Q = redQ[lrow][0] + redQ[lrow][1] + redQ[lrow][2] + redQ[lrow][3];
      float mu = S*(1.f/384.f);
      float var = Q*(1.f/384.f) - mu*mu;
      float rstd = rsqrtf(var + 1e-5f);
      unsigned char* lrowp = ln2 + (size_t)(nr[mi][r] - lnbase)*384;
      #pragma unroll
      for (int ni=0;ni<6;++ni){
        int col = wn*96 + ni*16 + fr;
        lrowp[col] = f2fp8((acc[mi][ni][r] - mu)*rstd*gv[ni] + b2v[ni]);
      }
    }
  }
}

// ------- MFMA windowed attention (R17 body + register-neutral V-staging fix) -------
__global__ __launch_bounds__(256)
void k_attn(const bf16* __restrict__ qkv, const float* __restrict__ comb,
            bf16* __restrict__ outp, int qs)
{
  const int wg   = xcd_swizzle(blockIdx.x, gridDim.x);
  const int head = wg % 12;
  const int win  = wg / 12;
  const int tid  = threadIdx.x;
  const int wave = tid>>6;
  const int lane = tid&63;
  const int l15 = lane & 15, l4 = lane>>4;
  __shared__ __align__(16) bf16 Vt[32*136];
  __shared__ __align__(16) bf16 P_buf[4][16*40];

  const int wq = win&7, hq=(win>>3)&7, dq=(win>>6)&3;
  const int cls = ((dq==3)?4:0) | ((hq==7)?2:0) | ((wq==7)?1:0);
  const float* combbase = comb + (size_t)(cls*12+head)*128*128;
  const bf16* qkvw_ = qkv + (size_t)win*98*qs;

  // V transpose staging: unit u -> token m = u&127 (contiguous across wave ->
  // writes spread across all 32 banks, 2-way = free), d0-chunk = (u>>7)*8.
  for (int u = tid; u < 512; u += 256){
    int m = u & 127, d0 = (u>>7)*8;
    int mc = m>97 ? 97 : m;
    s16x8 v = *(const s16x8*)(qkvw_ + (size_t)mc*qs + 768 + head*32 + d0);
    #pragma unroll
    for (int e=0;e<8;++e){ short sv = v[e]; Vt[(d0+e)*136 + m] = *(bf16*)&sv; }
  }
  s16x8 kb[8];
  #pragma unroll
  for (int j=0;j<8;++j){
    int tok = j*16 + l15; if (tok>97) tok = 97;
    kb[j] = *(const s16x8*)(qkvw_ + (size_t)tok*qs + 384 + head*32 + l4*8);
  }
  __syncthreads();

  const int c0 = wave*32;
  bf16* Pw = P_buf[wave];
  #pragma unroll
  for (int mi=0;mi<2;++mi){
    int q = c0 + mi*16 + l15; if (q>97) q=97;
    s16x8 aq = *(const s16x8*)(qkvw_ + (size_t)q*qs + head*32 + l4*8);
    f32x4v s[8];
    const float* cb = combbase + (size_t)(c0+mi*16+l4*4)*128 + l15;
    #pragma unroll
    for (int j=0;j<8;++j){
      f32x4v ci = { cb[j*16], cb[j*16+128], cb[j*16+256], cb[j*16+384] };
      s[j] = __builtin_amdgcn_mfma_f32_16x16x32_bf16(aq, kb[j], ci, 0,0,0);
    }
    float rinv[4];
    #pragma unroll
    for (int r=0;r<4;++r){
      float mx = s[0][r];
      #pragma unroll
      for (int j=1;j<8;++j) mx = fmaxf(mx, s[j][r]);
      mx = fmaxf(mx, __shfl_xor(mx,1));
      mx = fmaxf(mx, __shfl_xor(mx,2));
      mx = fmaxf(mx, __shfl_xor(mx,4));
      mx = fmaxf(mx, __shfl_xor(mx,8));
      float sum = 0.f;
      #pragma unroll
      for (int j=0;j<8;++j){ float e = __expf(s[j][r]-mx); s[j][r]=e; sum+=e; }
      sum += __shfl_xor(sum,1);
      sum += __shfl_xor(sum,2);
      sum += __shfl_xor(sum,4);
      sum += __shfl_xor(sum,8);
      rinv[r] = 1.f/sum;
    }
    f32x4v oacc[2] = {{0.f,0.f,0.f,0.f},{0.f,0.f,0.f,0.f}};
    #pragma unroll
    for (int ks=0; ks<4; ++ks){
      #pragma unroll
      for (int jj=0;jj<2;++jj)
        #pragma unroll
        for (int r=0;r<4;++r)
          Pw[(l4*4+r)*40 + jj*16 + l15] = f2bf(s[ks*2+jj][r]);
      s16x8 pa = *(const s16x8*)&Pw[l15*40 + l4*8];
      #pragma unroll
      for (int ni=0;ni<2;++ni){
        s16x8 vb = *(const s16x8*)&Vt[(ni*16+l15)*136 + ks*32 + l4*8];
        oacc[ni] = __builtin_amdgcn_mfma_f32_16x16x32_bf16(pa, vb, oacc[ni], 0,0,0);
      }
    }
    #pragma unroll
    for (int r=0;r<4;++r){
      int qo = c0 + mi*16 + l4*4 + r;
      if (qo < 98){
        bf16* orow = outp + ((size_t)win*98 + qo)*384 + head*32;
        #pragma unroll
        for (int ni=0;ni<2;++ni)
          orow[ni*16+l15] = f2bf(oacc[ni][r]*rinv[r]);
      }
    }
  }
}

extern "C" void kernel_launch(void* const* d_in, const int* in_sizes, int n_in,
                              void* d_out, int out_size, void* d_ws, size_t ws_size,
                              hipStream_t stream)
{
  const float* x     = (const float*)d_in[0];
  const float* n1g   = (const float*)d_in[1];
  const float* n1b   = (const float*)d_in[2];
  const float* qkvw  = (const float*)d_in[3];
  const float* qkvbv = (const float*)d_in[4];
  const float* rpb   = (const float*)d_in[5];
  const float* projw = (const float*)d_in[6];
  const float* projb = (const float*)d_in[7];
  const float* n2g   = (const float*)d_in[8];
  const float* n2b   = (const float*)d_in[9];
  const float* fc1w  = (const float*)d_in[10];
  const float* fc1b  = (const float*)d_in[11];
  const float* fc2w  = (const float*)d_in[12];
  const float* fc2b  = (const float*)d_in[13];
  float* out = (float*)d_out;

  char* ws = (char*)d_ws;
  size_t off = 0;
  auto alloc = [&](size_t bytes)->char*{
    char* p = ws + off; off += (bytes + 255) & ~(size_t)255; return p;
  };
  bf16*  wbf   = (bf16*)alloc((size_t)589824*2);            // qkv | proj (bf16)
  bf16*  wqkv  = wbf;
  bf16*  wproj = wbf + 442368;
  unsigned char* wfc1q = (unsigned char*)alloc(589824);     // fc1 fp8
  unsigned char* wfc2q = (unsigned char*)alloc(589824);     // fc2 fp8
  float* comb  = (float*)alloc((size_t)96*128*128*4);

  k_f2bf2<<<(589824+255)/256,256,0,stream>>>(qkvw, projw, wbf);
  k_f2fp8w<<<(589824+255)/256,256,0,stream>>>(fc1w, fc2w, wfc1q, wfc2q);
  k_comb<<<6144,256,0,stream>>>(rpb, comb);

  const size_t fused_need = off
      + (((size_t)100352*384*2  + 255) & ~(size_t)255)   // xw
      + (((size_t)100352*1536*2 + 255) & ~(size_t)255)   // bufA (qkv bf16 / fc1-out fp8)
      + (((size_t)100352*384    + 255) & ~(size_t)255);  // ln2 (fp8)
  if (ws_size >= fused_need){
    bf16* xw    = (bf16*)alloc((size_t)100352*384*2);
    bf16* bufA  = (bf16*)alloc((size_t)100352*1536*2);
    unsigned char* ln2 = (unsigned char*)alloc((size_t)100352*384);
    bf16* attno = bufA + (size_t)100352*1152;            // tail of bufA (bf16 region)
    unsigned char* mlp = (unsigned char*)bufA;           // fc1 fp8 output

    k_ln1<<<25088,256,0,stream>>>(x, n1g, n1b, xw, 0L);
    k_gemm192<3,6><<<784*6,256,0,stream>>>(xw, wqkv, qkvbv, nullptr, bufA, 1152, 6);
    k_attn<<<12*1024,256,0,stream>>>(bufA, comb, attno, 1152);
    k_projln2<12><<<784,512,0,stream>>>(attno, wproj, projb, x, n2g, n2b, out, ln2, 0L, 0L);
    k_gemm_fp8<1,3><<<784*8,256,0,stream>>>(ln2, wfc1q, fc1b, nullptr, mlp, 1536, 8);
    k_gemm_fp8<2,12><<<784*2,256,0,stream>>>(mlp, wfc2q, fc2b, out, (void*)out, 384, 2);
  } else {
    bf16* xw    = (bf16*)alloc((size_t)25088*384*2);
    bf16* bufA  = (bf16*)alloc((size_t)25088*1536*2);
    unsigned char* ln2 = (unsigned char*)alloc((size_t)25088*384);
    bf16* attno = bufA + (size_t)25088*1152;
    unsigned char* mlp = (unsigned char*)bufA;
    for (int b=0; b<4; ++b){
      long tbase = (long)b*25088;
      k_ln1<<<6272,256,0,stream>>>(x, n1g, n1b, xw, tbase);
      k_gemm192<3,6><<<196*6,256,0,stream>>>(xw, wqkv, qkvbv, nullptr, bufA, 1152, 6);
      k_attn<<<12*256,256,0,stream>>>(bufA, comb, attno, 1152);
      k_projln2<12><<<196,512,0,stream>>>(attno, wproj, projb, x, n2g, n2b, out, ln2, tbase, tbase);
      k_gemm_fp8<1,3><<<196*8,256,0,stream>>>(ln2, wfc1q, fc1b, nullptr, mlp, 1536, 8);
      float* resid = out + (size_t)b*25088*384;
      k_gemm_fp8<2,12><<<196*2,256,0,stream>>>(mlp, wfc2q, fc2b, resid, (void*)resid, 384, 2);
    }
  }
}

// Round 21
// 816.515 us; speedup vs baseline: 1.2458x; 1.0361x over previous
//
#include <hip/hip_runtime.h>
#include <hip/hip_bf16.h>
#include <hip/hip_fp8.h>
#include <cmath>

typedef __hip_bfloat16 bf16;
typedef __attribute__((ext_vector_type(8))) short s16x8;
typedef __attribute__((ext_vector_type(4))) float f32x4v;

__device__ __forceinline__ float bf2f(bf16 v){ return __bfloat162float(v); }
__device__ __forceinline__ bf16  f2bf(float v){ return __float2bfloat16(v); }
__device__ __forceinline__ unsigned char f2fp8(float v){
  __hip_fp8_e4m3 q(v);
  return *reinterpret_cast<unsigned char*>(&q);
}

__device__ __forceinline__ void gload16(const void* g, void* l){
  __builtin_amdgcn_global_load_lds((const __attribute__((address_space(1))) void*)g,
                                   (__attribute__((address_space(3))) void*)l,
                                   16, 0, 0);
}

// bijective XCD-chunk swizzle (m204)
__device__ __forceinline__ int xcd_swizzle(int bid, int nb){
  int q = nb >> 3, r = nb & 7;
  int xcd = bid & 7, idx = bid >> 3;
  return (xcd < r) ? (xcd*(q+1) + idx) : (r + xcd*q + idx);
}

// tanh-form GELU
__device__ __forceinline__ float gelu_f(float v){
  float y = 0.797884561f*(v + 0.044715f*v*v*v);
  float e = __expf(-2.f*y);
  return v * __builtin_amdgcn_rcpf(1.f + e);
}

// ---------------- proj fp32 -> bf16 ----------------
__global__ void k_f2bf1(const float* __restrict__ s0, bf16* __restrict__ out){
  int i = blockIdx.x*256 + threadIdx.x;
  if (i >= 147456) return;
  out[i] = f2bf(s0[i]);
}
// qkv | fc1 | fc2 fp32 -> fp8
__global__ void k_f2fp8w3(const float* __restrict__ sq, const float* __restrict__ s1,
                          const float* __restrict__ s2,
                          unsigned char* __restrict__ oq, unsigned char* __restrict__ o1,
                          unsigned char* __restrict__ o2){
  int i = blockIdx.x*256 + threadIdx.x;
  if (i >= 589824) return;
  if (i < 442368) oq[i] = f2fp8(sq[i]);
  o1[i] = f2fp8(s1[i]);
  o2[i] = f2fp8(s2[i]);
}

// ------- combined bias+mask table (f32): comb[cls(8)][head(12)][row 128][col 128] -------
__global__ void k_comb(const float* __restrict__ rpb, float* __restrict__ comb){
  int idx = blockIdx.x*256 + threadIdx.x;        // 96*128*128
  int col = idx & 127, row = (idx>>7)&127, clshead = idx>>14;
  int cls = clshead/12, head = clshead - cls*12;
  float v;
  if (row >= 98) v = 0.f;
  else if (col >= 98) v = -10000.f;
  else {
    int qd = row/49, qr = row%49, qh = qr/7, qw = qr%7;
    int kd = col/49, kr = col%49, kh = kr/7, kw = kr%7;
    int pbq = qd*169 + qh*13 + qw;
    int pbk = kd*169 + kh*13 + kw;
    int lq, lk;
    {
      int ld = (cls&4) ? (qd==0?1:2) : 0;
      int lh = (cls&2) ? (qh<4?1:2) : 0;
      int lw = (cls&1) ? (qw<4?1:2) : 0;
      lq = ld*9+lh*3+lw;
    }
    {
      int ld = (cls&4) ? (kd==0?1:2) : 0;
      int lh = (cls&2) ? (kh<4?1:2) : 0;
      int lw = (cls&1) ? (kw<4?1:2) : 0;
      lk = ld*9+lh*3+lw;
    }
    float bias = rpb[(pbq-pbk+253)*12 + head];
    v = bias + ((lq!=lk) ? -100.f : 0.f);
  }
  comb[idx] = v;
}

// ------- LN1 + cyclic shift + window partition -> fp8 xw -------
__global__ __launch_bounds__(256)
void k_ln1(const float* __restrict__ x, const float* __restrict__ g,
           const float* __restrict__ b, unsigned char* __restrict__ xw, long tbase)
{
  int tl = blockIdx.x*4 + (threadIdx.x>>6);
  long t = tbase + tl;
  int lane = threadIdx.x & 63;
  int win = (int)(t / 98), n = (int)(t % 98);
  int batch = win>>8;
  int wq = win & 7, hq = (win>>3)&7, dq = (win>>6)&3;
  int dr = n/49, rem = n%49, hr = rem/7, wr = rem%7;
  int d = dq*2+dr, h = hq*7+hr, w = wq*7+wr;
  int sd = (d+1)&7;
  int sh = h+3; if (sh>=56) sh-=56;
  int sw = w+3; if (sw>=56) sw-=56;
  const float* row = x + ((size_t)(((batch*8+sd)*56+sh)*56+sw))*384;
  float v[6]; float s=0.f, ss=0.f;
  int c0 = lane*6;
  #pragma unroll
  for (int i=0;i<6;++i){ float f = row[c0+i]; v[i]=f; s+=f; ss+=f*f; }
  #pragma unroll
  for (int o=32;o>0;o>>=1){ s += __shfl_xor(s,o); ss += __shfl_xor(ss,o); }
  float mu = s*(1.f/384.f);
  float var = ss*(1.f/384.f) - mu*mu;
  float rstd = rsqrtf(var + 1e-5f);
  unsigned char* orow = xw + (size_t)tl*384;
  #pragma unroll
  for (int i=0;i<6;++i){ int c=c0+i; orow[c] = f2fp8((v[i]-mu)*rstd*g[c] + b[c]); }
}

// ------- fp8 MFMA GEMM: tile 128x192, wave tile 64x96, BK=128 bytes -------
// EPI: 1 bias+GELU -> fp8; 2 bias+resid -> f32; 3 bias, scale cols<384 -> bf16 (QKV)
template<int EPI, int KTB>   // KTB = K/128
__global__ __launch_bounds__(256, 2)
void k_gemm_fp8(const unsigned char* __restrict__ A, const unsigned char* __restrict__ B,
                const float* __restrict__ bias, const float* __restrict__ resid,
                void* __restrict__ outp, int N, int nx)
{
  constexpr int K = KTB*128;                       // bytes per row
  __shared__ __align__(16) unsigned char As[2][128*128];   // 32 KB
  __shared__ __align__(16) unsigned char Bs[2][192*128];   // 48 KB
  const int tid = threadIdx.x;
  const int wave = tid>>6, lane = tid&63;
  const int wg = xcd_swizzle(blockIdx.x, gridDim.x);
  const int tn = wg % nx, tm = wg / nx;
  const int wm = wave>>1, wn = wave&1;
  const int fr = lane & 15, l4 = lane>>4;

  f32x4v acc[4][6];
  #pragma unroll
  for (int i=0;i<4;++i)
    #pragma unroll
    for (int j=0;j<6;++j)
      #pragma unroll
      for (int e=0;e<4;++e) acc[i][j][e] = 0.f;

  const int lr8 = lane>>3, lc8 = lane&7;
  const size_t lane_src = (size_t)lr8*K + (size_t)((lc8 ^ lr8)*16);
  const unsigned char* gA = A + ((size_t)tm*128 + wave*32)*K + lane_src;
  const unsigned char* gB = B + ((size_t)tn*192 + wave*48)*K + lane_src;

  auto stage = [&](int buf, int koff){
    #pragma unroll
    for (int j=0;j<4;++j)
      gload16(gA + (size_t)(j*8)*K + koff, &As[buf][(wave*32 + j*8)*128]);
    #pragma unroll
    for (int j=0;j<6;++j)
      gload16(gB + (size_t)(j*8)*K + koff, &Bs[buf][(wave*48 + j*8)*128]);
  };

  stage(0, 0);

  int roff[4];
  #pragma unroll
  for (int kk=0;kk<4;++kk)
    roff[kk] = (((kk*2 + (l4>>1)) ^ (fr & 7))<<4) + ((l4&1)<<3);

  #pragma unroll 2
  for (int kt=0; kt<KTB; ++kt){
    asm volatile("s_waitcnt vmcnt(0) lgkmcnt(0)" ::: "memory");
    __builtin_amdgcn_s_barrier();
    if (kt+1 < KTB) stage((kt+1)&1, (kt+1)*128);
    const unsigned char* Ab = As[kt&1];
    const unsigned char* Bb = Bs[kt&1];
    long af[4][4], bfr[6][4];
    #pragma unroll
    for (int i=0;i<4;++i){
      int ra = (wm*64 + i*16 + fr)*128;
      #pragma unroll
      for (int kk=0;kk<4;++kk) af[i][kk] = *(const long*)&Ab[ra + roff[kk]];
    }
    #pragma unroll
    for (int i=0;i<6;++i){
      int rb = (wn*96 + i*16 + fr)*128;
      #pragma unroll
      for (int kk=0;kk<4;++kk) bfr[i][kk] = *(const long*)&Bb[rb + roff[kk]];
    }
    #pragma unroll
    for (int mi=0;mi<4;++mi)
      #pragma unroll
      for (int ni=0;ni<6;++ni)
        #pragma unroll
        for (int kk=0;kk<4;++kk)
          acc[mi][ni] = __builtin_amdgcn_mfma_f32_16x16x32_fp8_fp8(af[mi][kk], bfr[ni][kk], acc[mi][ni], 0,0,0);
  }

  #pragma unroll
  for (int mi=0;mi<4;++mi){
    #pragma unroll
    for (int ni=0;ni<6;++ni){
      int col = tn*192 + wn*96 + ni*16 + fr;
      float bv = bias[col];
      int rowb = tm*128 + wm*64 + mi*16 + l4*4;
      #pragma unroll
      for (int r=0;r<4;++r){
        size_t idx = (size_t)(rowb+r)*N + col;
        float v = acc[mi][ni][r] + bv;
        if (EPI==1){
          ((unsigned char*)outp)[idx] = f2fp8(gelu_f(v));
        } else if (EPI==3){
          if (col < 384) v *= 0.17677669529663687f;
          ((bf16*)outp)[idx] = f2bf(v);
        } else {
          ((float*)outp)[idx] = v + resid[idx];
        }
      }
    }
  }
}

// ------- FUSED proj GEMM + residual + window-reverse scatter + LN2 (ln2 -> fp8) -------
template<int KT>
__global__ __launch_bounds__(512, 1)
void k_projln2(const bf16* __restrict__ A, const bf16* __restrict__ B,
               const float* __restrict__ bias, const float* __restrict__ x,
               const float* __restrict__ g, const float* __restrict__ b2,
               float* __restrict__ outx, unsigned char* __restrict__ ln2,
               long tbase, long lnbase)
{
  constexpr int K = KT*32;   // 384
  __shared__ __align__(16) bf16 As[2][128*32];
  __shared__ __align__(16) bf16 Bs[2][384*32];
  __shared__ float redS[128][4];
  __shared__ float redQ[128][4];
  const int tid = threadIdx.x;
  const int wave = tid>>6, lane = tid&63;
  const int tm = xcd_swizzle(blockIdx.x, gridDim.x);
  const int wm = wave>>2, wn = wave&3;
  const int fr = lane & 15, l4 = lane>>4;

  f32x4v acc[4][6];
  #pragma unroll
  for (int i=0;i<4;++i)
    #pragma unroll
    for (int j=0;j<6;++j)
      #pragma unroll
      for (int e=0;e<4;++e) acc[i][j][e] = 0.f;

  const int srow0 = lane>>2;
  const int scol_sw = (((lane&3) ^ ((lane>>3)&3)))*8;
  const bf16* gA = A + ((size_t)tm*128 + wave*16 + srow0)*K + scol_sw;
  const bf16* gB = B + ((size_t)(wave*16) + srow0)*K + scol_sw;

  auto stage = [&](int buf, int koff){
    gload16(gA + koff, &As[buf][wave*512]);
    #pragma unroll
    for (int j=0;j<3;++j)
      gload16(gB + (size_t)(128*j)*K + koff, &Bs[buf][(j*128 + wave*16)*32]);
  };

  stage(0, 0);
  const int fko_sw = ((l4 ^ ((fr>>1)&3)))*8;

  #pragma unroll 2
  for (int kt=0; kt<KT; ++kt){
    asm volatile("s_waitcnt vmcnt(0) lgkmcnt(0)" ::: "memory");
    __builtin_amdgcn_s_barrier();
    if (kt+1 < KT) stage((kt+1)&1, (kt+1)*32);
    const bf16* Ab = As[kt&1];
    const bf16* Bb = Bs[kt&1];
    s16x8 af[4], bfr[6];
    #pragma unroll
    for (int i=0;i<6;++i)
      bfr[i] = *(const s16x8*)&Bb[(wn*96 + i*16 + fr)*32 + fko_sw];
    #pragma unroll
    for (int i=0;i<4;++i)
      af[i] = *(const s16x8*)&Ab[(wm*64 + i*16 + fr)*32 + fko_sw];
    #pragma unroll
    for (int mi=0;mi<4;++mi)
      #pragma unroll
      for (int ni=0;ni<6;++ni)
        acc[mi][ni] = __builtin_amdgcn_mfma_f32_16x16x32_bf16(af[mi], bfr[ni], acc[mi][ni], 0,0,0);
    __builtin_amdgcn_s_barrier();
  }

  float bv[6];
  #pragma unroll
  for (int ni=0;ni<6;++ni) bv[ni] = bias[wn*96 + ni*16 + fr];

  long nr[4][4];
  #pragma unroll
  for (int mi=0;mi<4;++mi){
    #pragma unroll
    for (int r=0;r<4;++r){
      int lrow = wm*64 + mi*16 + l4*4 + r;
      int ti = (int)(tbase + (long)tm*128 + lrow);
      int win = ti/98, n = ti - win*98;
      int batch = win>>8;
      int wq = win&7, hq = (win>>3)&7, dq = (win>>6)&3;
      int dr = n/49, rem = n - dr*49, hr = rem/7, wr = rem - hr*7;
      int d = dq*2+dr, h = hq*7+hr, w = wq*7+wr;
      int sd = (d+1)&7;
      int sh = h+3; if (sh>=56) sh-=56;
      int sw = w+3; if (sw>=56) sw-=56;
      long nrow = (long)batch*25088 + (long)(sd*56+sh)*56 + sw;
      nr[mi][r] = nrow;
      const float* xrow = x + (size_t)nrow*384;
      float* orow = outx + (size_t)nrow*384;
      float s = 0.f, q = 0.f;
      #pragma unroll
      for (int ni=0;ni<6;++ni){
        int col = wn*96 + ni*16 + fr;
        float hvl = acc[mi][ni][r] + bv[ni] + xrow[col];
        orow[col] = hvl;
        acc[mi][ni][r] = hvl;
        s += hvl; q += hvl*hvl;
      }
      s += __shfl_xor(s,1); q += __shfl_xor(q,1);
      s += __shfl_xor(s,2); q += __shfl_xor(q,2);
      s += __shfl_xor(s,4); q += __shfl_xor(q,4);
      s += __shfl_xor(s,8); q += __shfl_xor(q,8);
      if (fr == 0){ redS[lrow][wn] = s; redQ[lrow][wn] = q; }
    }
  }
  __syncthreads();
  float gv[6], b2v[6];
  #pragma unroll
  for (int ni=0;ni<6;++ni){
    int col = wn*96 + ni*16 + fr;
    gv[ni] = g[col]; b2v[ni] = b2[col];
  }
  #pragma unroll
  for (int mi=0;mi<4;++mi){
    #pragma unroll
    for (int r=0;r<4;++r){
      int lrow = wm*64 + mi*16 + l4*4 + r;
      float S = redS[lrow][0] + redS[lrow][1] + redS[lrow][2] + redS[lrow][3];
      float Q = redQ[lrow][0] + redQ[lrow][1] + redQ[lrow][2] + redQ[lrow][3];
      float mu = S*(1.f/384.f);
      float var = Q*(1.f/384.f) - mu*mu;
      float rstd = rsqrtf(var + 1e-5f);
      unsigned char* lrowp = ln2 + (size_t)(nr[mi][r] - lnbase)*384;
      #pragma unroll
      for (int ni=0;ni<6;++ni){
        int col = wn*96 + ni*16 + fr;
        lrowp[col] = f2fp8((acc[mi][ni][r] - mu)*rstd*gv[ni] + b2v[ni]);
      }
    }
  }
}

// ------- MFMA windowed attention (R20 body, unchanged) -------
__global__ __launch_bounds__(256)
void k_attn(const bf16* __restrict__ qkv, const float* __restrict__ comb,
            bf16* __restrict__ outp, int qs)
{
  const int wg   = xcd_swizzle(blockIdx.x, gridDim.x);
  const int head = wg % 12;
  const int win  = wg / 12;
  const int tid  = threadIdx.x;
  const int wave = tid>>6;
  const int lane = tid&63;
  const int l15 = lane & 15, l4 = lane>>4;
  __shared__ __align__(16) bf16 Vt[32*136];
  __shared__ __align__(16) bf16 P_buf[4][16*40];

  const int wq = win&7, hq=(win>>3)&7, dq=(win>>6)&3;
  const int cls = ((dq==3)?4:0) | ((hq==7)?2:0) | ((wq==7)?1:0);
  const float* combbase = comb + (size_t)(cls*12+head)*128*128;
  const bf16* qkvw_ = qkv + (size_t)win*98*qs;

  for (int u = tid; u < 512; u += 256){
    int m = u & 127, d0 = (u>>7)*8;
    int mc = m>97 ? 97 : m;
    s16x8 v = *(const s16x8*)(qkvw_ + (size_t)mc*qs + 768 + head*32 + d0);
    #pragma unroll
    for (int e=0;e<8;++e){ short sv = v[e]; Vt[(d0+e)*136 + m] = *(bf16*)&sv; }
  }
  s16x8 kb[8];
  #pragma unroll
  for (int j=0;j<8;++j){
    int tok = j*16 + l15; if (tok>97) tok = 97;
    kb[j] = *(const s16x8*)(qkvw_ + (size_t)tok*qs + 384 + head*32 + l4*8);
  }
  __syncthreads();

  const int c0 = wave*32;
  bf16* Pw = P_buf[wave];
  #pragma unroll
  for (int mi=0;mi<2;++mi){
    int q = c0 + mi*16 + l15; if (q>97) q=97;
    s16x8 aq = *(const s16x8*)(qkvw_ + (size_t)q*qs + head*32 + l4*8);
    f32x4v s[8];
    const float* cb = combbase + (size_t)(c0+mi*16+l4*4)*128 + l15;
    #pragma unroll
    for (int j=0;j<8;++j){
      f32x4v ci = { cb[j*16], cb[j*16+128], cb[j*16+256], cb[j*16+384] };
      s[j] = __builtin_amdgcn_mfma_f32_16x16x32_bf16(aq, kb[j], ci, 0,0,0);
    }
    float rinv[4];
    #pragma unroll
    for (int r=0;r<4;++r){
      float mx = s[0][r];
      #pragma unroll
      for (int j=1;j<8;++j) mx = fmaxf(mx, s[j][r]);
      mx = fmaxf(mx, __shfl_xor(mx,1));
      mx = fmaxf(mx, __shfl_xor(mx,2));
      mx = fmaxf(mx, __shfl_xor(mx,4));
      mx = fmaxf(mx, __shfl_xor(mx,8));
      float sum = 0.f;
      #pragma unroll
      for (int j=0;j<8;++j){ float e = __expf(s[j][r]-mx); s[j][r]=e; sum+=e; }
      sum += __shfl_xor(sum,1);
      sum += __shfl_xor(sum,2);
      sum += __shfl_xor(sum,4);
      sum += __shfl_xor(sum,8);
      rinv[r] = 1.f/sum;
    }
    f32x4v oacc[2] = {{0.f,0.f,0.f,0.f},{0.f,0.f,0.f,0.f}};
    #pragma unroll
    for (int ks=0; ks<4; ++ks){
      #pragma unroll
      for (int jj=0;jj<2;++jj)
        #pragma unroll
        for (int r=0;r<4;++r)
          Pw[(l4*4+r)*40 + jj*16 + l15] = f2bf(s[ks*2+jj][r]);
      s16x8 pa = *(const s16x8*)&Pw[l15*40 + l4*8];
      #pragma unroll
      for (int ni=0;ni<2;++ni){
        s16x8 vb = *(const s16x8*)&Vt[(ni*16+l15)*136 + ks*32 + l4*8];
        oacc[ni] = __builtin_amdgcn_mfma_f32_16x16x32_bf16(pa, vb, oacc[ni], 0,0,0);
      }
    }
    #pragma unroll
    for (int r=0;r<4;++r){
      int qo = c0 + mi*16 + l4*4 + r;
      if (qo < 98){
        bf16* orow = outp + ((size_t)win*98 + qo)*384 + head*32;
        #pragma unroll
        for (int ni=0;ni<2;++ni)
          orow[ni*16+l15] = f2bf(oacc[ni][r]*rinv[r]);
      }
    }
  }
}

extern "C" void kernel_launch(void* const* d_in, const int* in_sizes, int n_in,
                              void* d_out, int out_size, void* d_ws, size_t ws_size,
                              hipStream_t stream)
{
  const float* x     = (const float*)d_in[0];
  const float* n1g   = (const float*)d_in[1];
  const float* n1b   = (const float*)d_in[2];
  const float* qkvw  = (const float*)d_in[3];
  const float* qkvbv = (const float*)d_in[4];
  const float* rpb   = (const float*)d_in[5];
  const float* projw = (const float*)d_in[6];
  const float* projb = (const float*)d_in[7];
  const float* n2g   = (const float*)d_in[8];
  const float* n2b   = (const float*)d_in[9];
  const float* fc1w  = (const float*)d_in[10];
  const float* fc1b  = (const float*)d_in[11];
  const float* fc2w  = (const float*)d_in[12];
  const float* fc2b  = (const float*)d_in[13];
  float* out = (float*)d_out;

  char* ws = (char*)d_ws;
  size_t off = 0;
  auto alloc = [&](size_t bytes)->char*{
    char* p = ws + off; off += (bytes + 255) & ~(size_t)255; return p;
  };
  bf16*  wproj = (bf16*)alloc((size_t)147456*2);            // proj bf16
  unsigned char* wqkvq = (unsigned char*)alloc(442368);     // qkv fp8
  unsigned char* wfc1q = (unsigned char*)alloc(589824);     // fc1 fp8
  unsigned char* wfc2q = (unsigned char*)alloc(589824);     // fc2 fp8
  float* comb  = (float*)alloc((size_t)96*128*128*4);

  k_f2bf1<<<(147456+255)/256,256,0,stream>>>(projw, wproj);
  k_f2fp8w3<<<(589824+255)/256,256,0,stream>>>(qkvw, fc1w, fc2w, wqkvq, wfc1q, wfc2q);
  k_comb<<<6144,256,0,stream>>>(rpb, comb);

  const size_t fused_need = off
      + (((size_t)100352*384    + 255) & ~(size_t)255)   // xw (fp8)
      + (((size_t)100352*1536*2 + 255) & ~(size_t)255)   // bufA (qkv bf16 / fc1-out fp8)
      + (((size_t)100352*384    + 255) & ~(size_t)255);  // ln2 (fp8)
  if (ws_size >= fused_need){
    unsigned char* xw = (unsigned char*)alloc((size_t)100352*384);
    bf16* bufA  = (bf16*)alloc((size_t)100352*1536*2);
    unsigned char* ln2 = (unsigned char*)alloc((size_t)100352*384);
    bf16* attno = bufA + (size_t)100352*1152;            // tail of bufA (bf16 region)
    unsigned char* mlp = (unsigned char*)bufA;           // fc1 fp8 output

    k_ln1<<<25088,256,0,stream>>>(x, n1g, n1b, xw, 0L);
    k_gemm_fp8<3,3><<<784*6,256,0,stream>>>(xw, wqkvq, qkvbv, nullptr, bufA, 1152, 6);
    k_attn<<<12*1024,256,0,stream>>>(bufA, comb, attno, 1152);
    k_projln2<12><<<784,512,0,stream>>>(attno, wproj, projb, x, n2g, n2b, out, ln2, 0L, 0L);
    k_gemm_fp8<1,3><<<784*8,256,0,stream>>>(ln2, wfc1q, fc1b, nullptr, mlp, 1536, 8);
    k_gemm_fp8<2,12><<<784*2,256,0,stream>>>(mlp, wfc2q, fc2b, out, (void*)out, 384, 2);
  } else {
    unsigned char* xw = (unsigned char*)alloc((size_t)25088*384);
    bf16* bufA  = (bf16*)alloc((size_t)25088*1536*2);
    unsigned char* ln2 = (unsigned char*)alloc((size_t)25088*384);
    bf16* attno = bufA + (size_t)25088*1152;
    unsigned char* mlp = (unsigned char*)bufA;
    for (int b=0; b<4; ++b){
      long tbase = (long)b*25088;
      k_ln1<<<6272,256,0,stream>>>(x, n1g, n1b, xw, tbase);
      k_gemm_fp8<3,3><<<196*6,256,0,stream>>>(xw, wqkvq, qkvbv, nullptr, bufA, 1152, 6);
      k_attn<<<12*256,256,0,stream>>>(bufA, comb, attno, 1152);
      k_projln2<12><<<196,512,0,stream>>>(attno, wproj, projb, x, n2g, n2b, out, ln2, tbase, tbase);
      k_gemm_fp8<1,3><<<196*8,256,0,stream>>>(ln2, wfc1q, fc1b, nullptr, mlp, 1536, 8);
      float* resid = out + (size_t)b*25088*384;
      k_gemm_fp8<2,12><<<196*2,256,0,stream>>>(mlp, wfc2q, fc2b, resid, (void*)resid, 384, 2);
    }
  }
}

// Round 22
// 784.740 us; speedup vs baseline: 1.2962x; 1.0405x over previous
//
#include <hip/hip_runtime.h>
#include <hip/hip_bf16.h>
#include <hip/hip_fp8.h>
#include <cmath>

typedef __hip_bfloat16 bf16;
typedef __attribute__((ext_vector_type(8))) short s16x8;
typedef __attribute__((ext_vector_type(4))) float f32x4v;

__device__ __forceinline__ float bf2f(bf16 v){ return __bfloat162float(v); }
__device__ __forceinline__ bf16  f2bf(float v){ return __float2bfloat16(v); }
__device__ __forceinline__ unsigned char f2fp8(float v){
  __hip_fp8_e4m3 q(v);
  return *reinterpret_cast<unsigned char*>(&q);
}

__device__ __forceinline__ void gload16(const void* g, void* l){
  __builtin_amdgcn_global_load_lds((const __attribute__((address_space(1))) void*)g,
                                   (__attribute__((address_space(3))) void*)l,
                                   16, 0, 0);
}

// bijective XCD-chunk swizzle (m204)
__device__ __forceinline__ int xcd_swizzle(int bid, int nb){
  int q = nb >> 3, r = nb & 7;
  int xcd = bid & 7, idx = bid >> 3;
  return (xcd < r) ? (xcd*(q+1) + idx) : (r + xcd*q + idx);
}

// tanh-form GELU
__device__ __forceinline__ float gelu_f(float v){
  float y = 0.797884561f*(v + 0.044715f*v*v*v);
  float e = __expf(-2.f*y);
  return v * __builtin_amdgcn_rcpf(1.f + e);
}

// qkv | proj | fc1 | fc2 fp32 -> fp8 (sizes 442368, 147456, 589824, 589824)
__global__ void k_f2fp8w4(const float* __restrict__ sq, const float* __restrict__ sp,
                          const float* __restrict__ s1, const float* __restrict__ s2,
                          unsigned char* __restrict__ oq, unsigned char* __restrict__ op,
                          unsigned char* __restrict__ o1, unsigned char* __restrict__ o2){
  int i = blockIdx.x*256 + threadIdx.x;
  if (i >= 589824) return;
  if (i < 442368) oq[i] = f2fp8(sq[i]);
  if (i < 147456) op[i] = f2fp8(sp[i]);
  o1[i] = f2fp8(s1[i]);
  o2[i] = f2fp8(s2[i]);
}

// ------- combined bias+mask table (f32): comb[cls(8)][head(12)][row 128][col 128] -------
__global__ void k_comb(const float* __restrict__ rpb, float* __restrict__ comb){
  int idx = blockIdx.x*256 + threadIdx.x;        // 96*128*128
  int col = idx & 127, row = (idx>>7)&127, clshead = idx>>14;
  int cls = clshead/12, head = clshead - cls*12;
  float v;
  if (row >= 98) v = 0.f;
  else if (col >= 98) v = -10000.f;
  else {
    int qd = row/49, qr = row%49, qh = qr/7, qw = qr%7;
    int kd = col/49, kr = col%49, kh = kr/7, kw = kr%7;
    int pbq = qd*169 + qh*13 + qw;
    int pbk = kd*169 + kh*13 + kw;
    int lq, lk;
    {
      int ld = (cls&4) ? (qd==0?1:2) : 0;
      int lh = (cls&2) ? (qh<4?1:2) : 0;
      int lw = (cls&1) ? (qw<4?1:2) : 0;
      lq = ld*9+lh*3+lw;
    }
    {
      int ld = (cls&4) ? (kd==0?1:2) : 0;
      int lh = (cls&2) ? (kh<4?1:2) : 0;
      int lw = (cls&1) ? (kw<4?1:2) : 0;
      lk = ld*9+lh*3+lw;
    }
    float bias = rpb[(pbq-pbk+253)*12 + head];
    v = bias + ((lq!=lk) ? -100.f : 0.f);
  }
  comb[idx] = v;
}

// ------- LN1 + cyclic shift + window partition -> fp8 xw -------
__global__ __launch_bounds__(256)
void k_ln1(const float* __restrict__ x, const float* __restrict__ g,
           const float* __restrict__ b, unsigned char* __restrict__ xw, long tbase)
{
  int tl = blockIdx.x*4 + (threadIdx.x>>6);
  long t = tbase + tl;
  int lane = threadIdx.x & 63;
  int win = (int)(t / 98), n = (int)(t % 98);
  int batch = win>>8;
  int wq = win & 7, hq = (win>>3)&7, dq = (win>>6)&3;
  int dr = n/49, rem = n%49, hr = rem/7, wr = rem%7;
  int d = dq*2+dr, h = hq*7+hr, w = wq*7+wr;
  int sd = (d+1)&7;
  int sh = h+3; if (sh>=56) sh-=56;
  int sw = w+3; if (sw>=56) sw-=56;
  const float* row = x + ((size_t)(((batch*8+sd)*56+sh)*56+sw))*384;
  float v[6]; float s=0.f, ss=0.f;
  int c0 = lane*6;
  #pragma unroll
  for (int i=0;i<6;++i){ float f = row[c0+i]; v[i]=f; s+=f; ss+=f*f; }
  #pragma unroll
  for (int o=32;o>0;o>>=1){ s += __shfl_xor(s,o); ss += __shfl_xor(ss,o); }
  float mu = s*(1.f/384.f);
  float var = ss*(1.f/384.f) - mu*mu;
  float rstd = rsqrtf(var + 1e-5f);
  unsigned char* orow = xw + (size_t)tl*384;
  #pragma unroll
  for (int i=0;i<6;++i){ int c=c0+i; orow[c] = f2fp8((v[i]-mu)*rstd*g[c] + b[c]); }
}

// ------- fp8 MFMA GEMM: tile 128x192, wave tile 64x96, BK=128 bytes -------
// EPI: 1 bias+GELU -> fp8; 2 bias+resid -> f32; 3 bias, scale cols<384 -> bf16 (QKV)
template<int EPI, int KTB>   // KTB = K/128
__global__ __launch_bounds__(256, 2)
void k_gemm_fp8(const unsigned char* __restrict__ A, const unsigned char* __restrict__ B,
                const float* __restrict__ bias, const float* __restrict__ resid,
                void* __restrict__ outp, int N, int nx)
{
  constexpr int K = KTB*128;                       // bytes per row
  __shared__ __align__(16) unsigned char As[2][128*128];   // 32 KB
  __shared__ __align__(16) unsigned char Bs[2][192*128];   // 48 KB
  const int tid = threadIdx.x;
  const int wave = tid>>6, lane = tid&63;
  const int wg = xcd_swizzle(blockIdx.x, gridDim.x);
  const int tn = wg % nx, tm = wg / nx;
  const int wm = wave>>1, wn = wave&1;
  const int fr = lane & 15, l4 = lane>>4;

  f32x4v acc[4][6];
  #pragma unroll
  for (int i=0;i<4;++i)
    #pragma unroll
    for (int j=0;j<6;++j)
      #pragma unroll
      for (int e=0;e<4;++e) acc[i][j][e] = 0.f;

  const int lr8 = lane>>3, lc8 = lane&7;
  const size_t lane_src = (size_t)lr8*K + (size_t)((lc8 ^ lr8)*16);
  const unsigned char* gA = A + ((size_t)tm*128 + wave*32)*K + lane_src;
  const unsigned char* gB = B + ((size_t)tn*192 + wave*48)*K + lane_src;

  auto stage = [&](int buf, int koff){
    #pragma unroll
    for (int j=0;j<4;++j)
      gload16(gA + (size_t)(j*8)*K + koff, &As[buf][(wave*32 + j*8)*128]);
    #pragma unroll
    for (int j=0;j<6;++j)
      gload16(gB + (size_t)(j*8)*K + koff, &Bs[buf][(wave*48 + j*8)*128]);
  };

  stage(0, 0);

  int roff[4];
  #pragma unroll
  for (int kk=0;kk<4;++kk)
    roff[kk] = (((kk*2 + (l4>>1)) ^ (fr & 7))<<4) + ((l4&1)<<3);

  #pragma unroll 2
  for (int kt=0; kt<KTB; ++kt){
    asm volatile("s_waitcnt vmcnt(0) lgkmcnt(0)" ::: "memory");
    __builtin_amdgcn_s_barrier();
    if (kt+1 < KTB) stage((kt+1)&1, (kt+1)*128);
    const unsigned char* Ab = As[kt&1];
    const unsigned char* Bb = Bs[kt&1];
    long af[4][4], bfr[6][4];
    #pragma unroll
    for (int i=0;i<4;++i){
      int ra = (wm*64 + i*16 + fr)*128;
      #pragma unroll
      for (int kk=0;kk<4;++kk) af[i][kk] = *(const long*)&Ab[ra + roff[kk]];
    }
    #pragma unroll
    for (int i=0;i<6;++i){
      int rb = (wn*96 + i*16 + fr)*128;
      #pragma unroll
      for (int kk=0;kk<4;++kk) bfr[i][kk] = *(const long*)&Bb[rb + roff[kk]];
    }
    #pragma unroll
    for (int mi=0;mi<4;++mi)
      #pragma unroll
      for (int ni=0;ni<6;++ni)
        #pragma unroll
        for (int kk=0;kk<4;++kk)
          acc[mi][ni] = __builtin_amdgcn_mfma_f32_16x16x32_fp8_fp8(af[mi][kk], bfr[ni][kk], acc[mi][ni], 0,0,0);
  }

  #pragma unroll
  for (int mi=0;mi<4;++mi){
    #pragma unroll
    for (int ni=0;ni<6;++ni){
      int col = tn*192 + wn*96 + ni*16 + fr;
      float bv = bias[col];
      int rowb = tm*128 + wm*64 + mi*16 + l4*4;
      #pragma unroll
      for (int r=0;r<4;++r){
        size_t idx = (size_t)(rowb+r)*N + col;
        float v = acc[mi][ni][r] + bv;
        if (EPI==1){
          ((unsigned char*)outp)[idx] = f2fp8(gelu_f(v));
        } else if (EPI==3){
          if (col < 384) v *= 0.17677669529663687f;
          ((bf16*)outp)[idx] = f2bf(v);
        } else {
          ((float*)outp)[idx] = v + resid[idx];
        }
      }
    }
  }
}

// ------- FUSED fp8 proj GEMM + residual + window-reverse scatter + LN2 (ln2 -> fp8) -------
// A = attn output (fp8, 384 B rows), B = proj weight (fp8). BK=128 B -> 3 K-steps.
// 8 waves (2M x 4N), wave tile 64x96. Same epilogue as before.
__global__ __launch_bounds__(512, 1)
void k_projln2f8(const unsigned char* __restrict__ A, const unsigned char* __restrict__ B,
                 const float* __restrict__ bias, const float* __restrict__ x,
                 const float* __restrict__ g, const float* __restrict__ b2,
                 float* __restrict__ outx, unsigned char* __restrict__ ln2,
                 long tbase, long lnbase)
{
  constexpr int K = 384;   // bytes per row
  __shared__ __align__(16) unsigned char As[2][128*128];   // 16 KB x2
  __shared__ __align__(16) unsigned char Bs[2][384*128];   // 48 KB x2
  __shared__ float redS[128][4];
  __shared__ float redQ[128][4];
  const int tid = threadIdx.x;
  const int wave = tid>>6, lane = tid&63;
  const int tm = xcd_swizzle(blockIdx.x, gridDim.x);
  const int wm = wave>>2, wn = wave&3;     // wave tile 64x96
  const int fr = lane & 15, l4 = lane>>4;

  f32x4v acc[4][6];
  #pragma unroll
  for (int i=0;i<4;++i)
    #pragma unroll
    for (int j=0;j<6;++j)
      #pragma unroll
      for (int e=0;e<4;++e) acc[i][j][e] = 0.f;

  const int lr8 = lane>>3, lc8 = lane&7;
  const size_t lane_src = (size_t)lr8*K + (size_t)((lc8 ^ lr8)*16);
  const unsigned char* gA = A + ((size_t)tm*128 + wave*16)*K + lane_src;
  const unsigned char* gB = B + ((size_t)(wave*48))*K + lane_src;

  auto stage = [&](int buf, int koff){
    #pragma unroll
    for (int j=0;j<2;++j)
      gload16(gA + (size_t)(j*8)*K + koff, &As[buf][(wave*16 + j*8)*128]);
    #pragma unroll
    for (int j=0;j<6;++j)
      gload16(gB + (size_t)(j*8)*K + koff, &Bs[buf][(wave*48 + j*8)*128]);
  };

  stage(0, 0);

  int roff[4];
  #pragma unroll
  for (int kk=0;kk<4;++kk)
    roff[kk] = (((kk*2 + (l4>>1)) ^ (fr & 7))<<4) + ((l4&1)<<3);

  #pragma unroll
  for (int kt=0; kt<3; ++kt){
    asm volatile("s_waitcnt vmcnt(0) lgkmcnt(0)" ::: "memory");
    __builtin_amdgcn_s_barrier();
    if (kt+1 < 3) stage((kt+1)&1, (kt+1)*128);
    const unsigned char* Ab = As[kt&1];
    const unsigned char* Bb = Bs[kt&1];
    long af[4][4], bfr[6][4];
    #pragma unroll
    for (int i=0;i<4;++i){
      int ra = (wm*64 + i*16 + fr)*128;
      #pragma unroll
      for (int kk=0;kk<4;++kk) af[i][kk] = *(const long*)&Ab[ra + roff[kk]];
    }
    #pragma unroll
    for (int i=0;i<6;++i){
      int rb = (wn*96 + i*16 + fr)*128;
      #pragma unroll
      for (int kk=0;kk<4;++kk) bfr[i][kk] = *(const long*)&Bb[rb + roff[kk]];
    }
    #pragma unroll
    for (int mi=0;mi<4;++mi)
      #pragma unroll
      for (int ni=0;ni<6;++ni)
        #pragma unroll
        for (int kk=0;kk<4;++kk)
          acc[mi][ni] = __builtin_amdgcn_mfma_f32_16x16x32_fp8_fp8(af[mi][kk], bfr[ni][kk], acc[mi][ni], 0,0,0);
  }

  float bv[6];
  #pragma unroll
  for (int ni=0;ni<6;++ni) bv[ni] = bias[wn*96 + ni*16 + fr];

  long nr[4][4];
  #pragma unroll
  for (int mi=0;mi<4;++mi){
    #pragma unroll
    for (int r=0;r<4;++r){
      int lrow = wm*64 + mi*16 + l4*4 + r;
      int ti = (int)(tbase + (long)tm*128 + lrow);
      int win = ti/98, n = ti - win*98;
      int batch = win>>8;
      int wq = win&7, hq = (win>>3)&7, dq = (win>>6)&3;
      int dr = n/49, rem = n - dr*49, hr = rem/7, wr = rem - hr*7;
      int d = dq*2+dr, h = hq*7+hr, w = wq*7+wr;
      int sd = (d+1)&7;
      int sh = h+3; if (sh>=56) sh-=56;
      int sw = w+3; if (sw>=56) sw-=56;
      long nrow = (long)batch*25088 + (long)(sd*56+sh)*56 + sw;
      nr[mi][r] = nrow;
      const float* xrow = x + (size_t)nrow*384;
      float* orow = outx + (size_t)nrow*384;
      float s = 0.f, q = 0.f;
      #pragma unroll
      for (int ni=0;ni<6;++ni){
        int col = wn*96 + ni*16 + fr;
        float hvl = acc[mi][ni][r] + bv[ni] + xrow[col];
        orow[col] = hvl;
        acc[mi][ni][r] = hvl;
        s += hvl; q += hvl*hvl;
      }
      s += __shfl_xor(s,1); q += __shfl_xor(q,1);
      s += __shfl_xor(s,2); q += __shfl_xor(q,2);
      s += __shfl_xor(s,4); q += __shfl_xor(q,4);
      s += __shfl_xor(s,8); q += __shfl_xor(q,8);
      if (fr == 0){ redS[lrow][wn] = s; redQ[lrow][wn] = q; }
    }
  }
  __syncthreads();
  float gv[6], b2v[6];
  #pragma unroll
  for (int ni=0;ni<6;++ni){
    int col = wn*96 + ni*16 + fr;
    gv[ni] = g[col]; b2v[ni] = b2[col];
  }
  #pragma unroll
  for (int mi=0;mi<4;++mi){
    #pragma unroll
    for (int r=0;r<4;++r){
      int lrow = wm*64 + mi*16 + l4*4 + r;
      float S = redS[lrow][0] + redS[lrow][1] + redS[lrow][2] + redS[lrow][3];
      float Q = redQ[lrow][0] + redQ[lrow][1] + redQ[lrow][2] + redQ[lrow][3];
      float mu = S*(1.f/384.f);
      float var = Q*(1.f/384.f) - mu*mu;
      float rstd = rsqrtf(var + 1e-5f);
      unsigned char* lrowp = ln2 + (size_t)(nr[mi][r] - lnbase)*384;
      #pragma unroll
      for (int ni=0;ni<6;++ni){
        int col = wn*96 + ni*16 + fr;
        lrowp[col] = f2fp8((acc[mi][ni][r] - mu)*rstd*gv[ni] + b2v[ni]);
      }
    }
  }
}

// ------- MFMA windowed attention (R20 body; output -> fp8) -------
__global__ __launch_bounds__(256)
void k_attn(const bf16* __restrict__ qkv, const float* __restrict__ comb,
            unsigned char* __restrict__ outp, int qs)
{
  const int wg   = xcd_swizzle(blockIdx.x, gridDim.x);
  const int head = wg % 12;
  const int win  = wg / 12;
  const int tid  = threadIdx.x;
  const int wave = tid>>6;
  const int lane = tid&63;
  const int l15 = lane & 15, l4 = lane>>4;
  __shared__ __align__(16) bf16 Vt[32*136];
  __shared__ __align__(16) bf16 P_buf[4][16*40];

  const int wq = win&7, hq=(win>>3)&7, dq=(win>>6)&3;
  const int cls = ((dq==3)?4:0) | ((hq==7)?2:0) | ((wq==7)?1:0);
  const float* combbase = comb + (size_t)(cls*12+head)*128*128;
  const bf16* qkvw_ = qkv + (size_t)win*98*qs;

  for (int u = tid; u < 512; u += 256){
    int m = u & 127, d0 = (u>>7)*8;
    int mc = m>97 ? 97 : m;
    s16x8 v = *(const s16x8*)(qkvw_ + (size_t)mc*qs + 768 + head*32 + d0);
    #pragma unroll
    for (int e=0;e<8;++e){ short sv = v[e]; Vt[(d0+e)*136 + m] = *(bf16*)&sv; }
  }
  s16x8 kb[8];
  #pragma unroll
  for (int j=0;j<8;++j){
    int tok = j*16 + l15; if (tok>97) tok = 97;
    kb[j] = *(const s16x8*)(qkvw_ + (size_t)tok*qs + 384 + head*32 + l4*8);
  }
  __syncthreads();

  const int c0 = wave*32;
  bf16* Pw = P_buf[wave];
  #pragma unroll
  for (int mi=0;mi<2;++mi){
    int q = c0 + mi*16 + l15; if (q>97) q=97;
    s16x8 aq = *(const s16x8*)(qkvw_ + (size_t)q*qs + head*32 + l4*8);
    f32x4v s[8];
    const float* cb = combbase + (size_t)(c0+mi*16+l4*4)*128 + l15;
    #pragma unroll
    for (int j=0;j<8;++j){
      f32x4v ci = { cb[j*16], cb[j*16+128], cb[j*16+256], cb[j*16+384] };
      s[j] = __builtin_amdgcn_mfma_f32_16x16x32_bf16(aq, kb[j], ci, 0,0,0);
    }
    float rinv[4];
    #pragma unroll
    for (int r=0;r<4;++r){
      float mx = s[0][r];
      #pragma unroll
      for (int j=1;j<8;++j) mx = fmaxf(mx, s[j][r]);
      mx = fmaxf(mx, __shfl_xor(mx,1));
      mx = fmaxf(mx, __shfl_xor(mx,2));
      mx = fmaxf(mx, __shfl_xor(mx,4));
      mx = fmaxf(mx, __shfl_xor(mx,8));
      float sum = 0.f;
      #pragma unroll
      for (int j=0;j<8;++j){ float e = __expf(s[j][r]-mx); s[j][r]=e; sum+=e; }
      sum += __shfl_xor(sum,1);
      sum += __shfl_xor(sum,2);
      sum += __shfl_xor(sum,4);
      sum += __shfl_xor(sum,8);
      rinv[r] = 1.f/sum;
    }
    f32x4v oacc[2] = {{0.f,0.f,0.f,0.f},{0.f,0.f,0.f,0.f}};
    #pragma unroll
    for (int ks=0; ks<4; ++ks){
      #pragma unroll
      for (int jj=0;jj<2;++jj)
        #pragma unroll
        for (int r=0;r<4;++r)
          Pw[(l4*4+r)*40 + jj*16 + l15] = f2bf(s[ks*2+jj][r]);
      s16x8 pa = *(const s16x8*)&Pw[l15*40 + l4*8];
      #pragma unroll
      for (int ni=0;ni<2;++ni){
        s16x8 vb = *(const s16x8*)&Vt[(ni*16+l15)*136 + ks*32 + l4*8];
        oacc[ni] = __builtin_amdgcn_mfma_f32_16x16x32_bf16(pa, vb, oacc[ni], 0,0,0);
      }
    }
    #pragma unroll
    for (int r=0;r<4;++r){
      int qo = c0 + mi*16 + l4*4 + r;
      if (qo < 98){
        unsigned char* orow = outp + ((size_t)win*98 + qo)*384 + head*32;
        #pragma unroll
        for (int ni=0;ni<2;++ni)
          orow[ni*16+l15] = f2fp8(oacc[ni][r]*rinv[r]);
      }
    }
  }
}

extern "C" void kernel_launch(void* const* d_in, const int* in_sizes, int n_in,
                              void* d_out, int out_size, void* d_ws, size_t ws_size,
                              hipStream_t stream)
{
  const float* x     = (const float*)d_in[0];
  const float* n1g   = (const float*)d_in[1];
  const float* n1b   = (const float*)d_in[2];
  const float* qkvw  = (const float*)d_in[3];
  const float* qkvbv = (const float*)d_in[4];
  const float* rpb   = (const float*)d_in[5];
  const float* projw = (const float*)d_in[6];
  const float* projb = (const float*)d_in[7];
  const float* n2g   = (const float*)d_in[8];
  const float* n2b   = (const float*)d_in[9];
  const float* fc1w  = (const float*)d_in[10];
  const float* fc1b  = (const float*)d_in[11];
  const float* fc2w  = (const float*)d_in[12];
  const float* fc2b  = (const float*)d_in[13];
  float* out = (float*)d_out;

  char* ws = (char*)d_ws;
  size_t off = 0;
  auto alloc = [&](size_t bytes)->char*{
    char* p = ws + off; off += (bytes + 255) & ~(size_t)255; return p;
  };
  unsigned char* wqkvq = (unsigned char*)alloc(442368);     // qkv fp8
  unsigned char* wprojq= (unsigned char*)alloc(147456);     // proj fp8
  unsigned char* wfc1q = (unsigned char*)alloc(589824);     // fc1 fp8
  unsigned char* wfc2q = (unsigned char*)alloc(589824);     // fc2 fp8
  float* comb  = (float*)alloc((size_t)96*128*128*4);

  k_f2fp8w4<<<(589824+255)/256,256,0,stream>>>(qkvw, projw, fc1w, fc2w,
                                               wqkvq, wprojq, wfc1q, wfc2q);
  k_comb<<<6144,256,0,stream>>>(rpb, comb);

  const size_t fused_need = off
      + (((size_t)100352*384    + 255) & ~(size_t)255)   // xw (fp8)
      + (((size_t)100352*1536*2 + 255) & ~(size_t)255)   // bufA (qkv bf16 / fc1-out fp8)
      + (((size_t)100352*384    + 255) & ~(size_t)255);  // ln2 (fp8)
  if (ws_size >= fused_need){
    unsigned char* xw = (unsigned char*)alloc((size_t)100352*384);
    bf16* bufA  = (bf16*)alloc((size_t)100352*1536*2);
    unsigned char* ln2 = (unsigned char*)alloc((size_t)100352*384);
    unsigned char* attno = (unsigned char*)(bufA + (size_t)100352*1152); // tail of bufA
    unsigned char* mlp = (unsigned char*)bufA;           // fc1 fp8 output

    k_ln1<<<25088,256,0,stream>>>(x, n1g, n1b, xw, 0L);
    k_gemm_fp8<3,3><<<784*6,256,0,stream>>>(xw, wqkvq, qkvbv, nullptr, bufA, 1152, 6);
    k_attn<<<12*1024,256,0,stream>>>(bufA, comb, attno, 1152);
    k_projln2f8<<<784,512,0,stream>>>(attno, wprojq, projb, x, n2g, n2b, out, ln2, 0L, 0L);
    k_gemm_fp8<1,3><<<784*8,256,0,stream>>>(ln2, wfc1q, fc1b, nullptr, mlp, 1536, 8);
    k_gemm_fp8<2,12><<<784*2,256,0,stream>>>(mlp, wfc2q, fc2b, out, (void*)out, 384, 2);
  } else {
    unsigned char* xw = (unsigned char*)alloc((size_t)25088*384);
    bf16* bufA  = (bf16*)alloc((size_t)25088*1536*2);
    unsigned char* ln2 = (unsigned char*)alloc((size_t)25088*384);
    unsigned char* attno = (unsigned char*)(bufA + (size_t)25088*1152);
    unsigned char* mlp = (unsigned char*)bufA;
    for (int b=0; b<4; ++b){
      long tbase = (long)b*25088;
      k_ln1<<<6272,256,0,stream>>>(x, n1g, n1b, xw, tbase);
      k_gemm_fp8<3,3><<<196*6,256,0,stream>>>(xw, wqkvq, qkvbv, nullptr, bufA, 1152, 6);
      k_attn<<<12*256,256,0,stream>>>(bufA, comb, attno, 1152);
      k_projln2f8<<<196,512,0,stream>>>(attno, wprojq, projb, x, n2g, n2b, out, ln2, tbase, tbase);
      k_gemm_fp8<1,3><<<196*8,256,0,stream>>>(ln2, wfc1q, fc1b, nullptr, mlp, 1536, 8);
      float* resid = out + (size_t)b*25088*384;
      k_gemm_fp8<2,12><<<196*2,256,0,stream>>>(mlp, wfc2q, fc2b, resid, (void*)resid, 384, 2);
    }
  }
}